// Round 10
// baseline (175.650 us; speedup 1.0000x reference)
//
#include <hip/hip_runtime.h>

#define C_   512
#define HW_  4096
#define NTOK 8192
#define PZ_  16777216L   // Pexp batch stride (elems) in big mode

typedef __attribute__((ext_vector_type(8))) short bf16x8;
typedef __attribute__((ext_vector_type(4))) float f32x4;
typedef unsigned short u16;

#define MFMA16 __builtin_amdgcn_mfma_f32_16x16x32_bf16

__device__ __forceinline__ u16 f2bf(float f) {
  unsigned int u = __float_as_uint(f);
  u += 0x7fffu + ((u >> 16) & 1u);
  return (u16)(u >> 16);
}

__device__ __forceinline__ float bf2f(u16 v) {
  return __uint_as_float((unsigned)v << 16);
}

__device__ __forceinline__ void gld_lds16(const u16* g, u16* l) {
  __builtin_amdgcn_global_load_lds(
      (const __attribute__((address_space(1))) void*)g,
      (__attribute__((address_space(3))) void*)l, 16, 0, 0);
}

// 128^2-kernel swizzle (8-chunk rows): chunk o stored at o ^ (row&7)
__device__ __forceinline__ const u16* swz(const u16* base, int row, int col, int ldu16) {
  return base + (size_t)row * ldu16 + ((((col >> 3) ^ (row & 7)) << 3) | (col & 7));
}

// ---------------- 256^2 8-wave counted-vmcnt pipeline pieces ----------------
// LDS tile = [256 rows][32 k] u16, 4 chunks of 16B per row.
// Swizzle: physical chunk = logical ^ ((row>>1)&3)  -> 2-way banks (free).
__device__ __forceinline__ void stage256(const u16* Ab, const u16* Bb,
                                         int lda_, int ldb_, int k0,
                                         u16* asb, u16* bsb, int t) {
  #pragma unroll
  for (int ld = 0; ld < 2; ++ld) {
    const int c = ld * 512 + t;
    const int row = c >> 2;
    const int off = (((c & 3) ^ ((row >> 1) & 3)) << 3);
    gld_lds16(Ab + (size_t)row * lda_ + k0 + off, asb + c * 8);
    gld_lds16(Bb + (size_t)row * ldb_ + k0 + off, bsb + c * 8);
  }
}

__device__ __forceinline__ bf16x8 frag256(const u16* buf, int row, int lq) {
  return *(const bf16x8*)(buf + row * 32 + ((lq ^ ((row >> 1) & 3)) << 3));
}

// counted wait: tiles t+1..t+3 (4 loads each) may stay in flight; tile t done.
__device__ __forceinline__ void vmwait256(int rem) {
  if (rem >= 3)      asm volatile("s_waitcnt vmcnt(12)" ::: "memory");
  else if (rem == 2) asm volatile("s_waitcnt vmcnt(8)"  ::: "memory");
  else if (rem == 1) asm volatile("s_waitcnt vmcnt(4)"  ::: "memory");
  else               asm volatile("s_waitcnt vmcnt(0)"  ::: "memory");
}

#define RING_BODY(NT, LDA, LDB, KBEG)                                          \
  stage256(Ab, Bb, LDA, LDB, (KBEG), &As[0][0], &Bs[0][0], t);                 \
  stage256(Ab, Bb, LDA, LDB, (KBEG) + 32, &As[1][0], &Bs[1][0], t);            \
  stage256(Ab, Bb, LDA, LDB, (KBEG) + 64, &As[2][0], &Bs[2][0], t);            \
  for (int tt = 0; tt < (NT); ++tt) {                                          \
    if (tt + 3 < (NT))                                                         \
      stage256(Ab, Bb, LDA, LDB, (KBEG) + (tt + 3) * 32,                       \
               &As[(tt + 3) & 3][0], &Bs[(tt + 3) & 3][0], t);                 \
    vmwait256((NT) - 1 - tt);                                                  \
    __builtin_amdgcn_sched_barrier(0);                                         \
    __builtin_amdgcn_s_barrier();                                              \
    __builtin_amdgcn_sched_barrier(0);                                         \
    const u16* al = &As[tt & 3][0];                                            \
    const u16* bl = &Bs[tt & 3][0];                                            \
    bf16x8 af[8], bf[4];                                                       \
    _Pragma("unroll")                                                          \
    for (int fr = 0; fr < 8; ++fr) af[fr] = frag256(al, wr * 128 + fr * 16 + lr, lq); \
    _Pragma("unroll")                                                          \
    for (int fc = 0; fc < 4; ++fc) bf[fc] = frag256(bl, wc * 64 + fc * 16 + lr, lq);  \
    __builtin_amdgcn_s_setprio(1);                                             \
    _Pragma("unroll")                                                          \
    for (int fr = 0; fr < 8; ++fr)                                             \
      _Pragma("unroll")                                                        \
      for (int fc = 0; fc < 4; ++fc)                                           \
        acc[fr][fc] = MFMA16(af[fr], bf[fc], acc[fr][fc], 0, 0, 0);            \
    __builtin_amdgcn_s_setprio(0);                                             \
    __builtin_amdgcn_sched_barrier(0);                                         \
    __builtin_amdgcn_s_barrier();                                              \
    __builtin_amdgcn_sched_barrier(0);                                         \
  }

// ---------------- weight fp32 -> bf16 cast (4 matrices of 512x512) ----------
__global__ void wcast_kernel(const float* __restrict__ a, const float* __restrict__ b,
                             const float* __restrict__ c, const float* __restrict__ d,
                             u16* __restrict__ out) {
  int gid = blockIdx.x * 256 + threadIdx.x;   // 262144 threads, 4 floats each
  int which = gid >> 16;
  const float* src = which == 0 ? a : which == 1 ? b : which == 2 ? c : d;
  int loc = (gid & 65535) * 4;
  float4 v = *(const float4*)(src + loc);
  ushort4 o;
  o.x = f2bf(v.x); o.y = f2bf(v.y); o.z = f2bf(v.z); o.w = f2bf(v.w);
  *(ushort4*)(out + ((size_t)which << 18) + loc) = o;
}

// ---------------- GroupNorm stats stage1: (group, chunk) partials -----------
__global__ __launch_bounds__(256) void gn_stats1_kernel(const float* __restrict__ x,
                                                        float* __restrict__ gpart) {
  const float4* p = (const float4*)(x + (size_t)blockIdx.x * 65536 + blockIdx.y * 8192);
  float s = 0.0f, ss = 0.0f;
  for (int i = threadIdx.x; i < 2048; i += 256) {
    float4 v = p[i];
    s  += v.x + v.y + v.z + v.w;
    ss += v.x * v.x + v.y * v.y + v.z * v.z + v.w * v.w;
  }
  #pragma unroll
  for (int m = 1; m < 64; m <<= 1) { s += __shfl_xor(s, m); ss += __shfl_xor(ss, m); }
  __shared__ float rs[4], rss[4];
  const int wv = threadIdx.x >> 6;
  if ((threadIdx.x & 63) == 0) { rs[wv] = s; rss[wv] = ss; }
  __syncthreads();
  if (threadIdx.x == 0) {
    gpart[(blockIdx.x * 8 + blockIdx.y) * 2]     = rs[0] + rs[1] + rs[2] + rs[3];
    gpart[(blockIdx.x * 8 + blockIdx.y) * 2 + 1] = rss[0] + rss[1] + rss[2] + rss[3];
  }
}

// ---------------- GN apply (stage2 folded) + transpose to hT[8192][512] -----
__global__ __launch_bounds__(256) void gn_apply_kernel(const float* __restrict__ x,
                                                       const float* __restrict__ gnw,
                                                       const float* __restrict__ gnb,
                                                       const float* __restrict__ gpart,
                                                       u16* __restrict__ hT) {
  const int b = blockIdx.z, c0 = blockIdx.y * 64, hw0 = blockIdx.x * 64;
  const int t = threadIdx.x;
  __shared__ float tile[64][65];
  __shared__ float gmean[4], grstd[4];
  if (t < 4) {
    const int g = b * 32 + (c0 >> 4) + t;
    float s = 0.0f, ss = 0.0f;
    #pragma unroll
    for (int cch = 0; cch < 8; ++cch) {
      s  += gpart[(g * 8 + cch) * 2];
      ss += gpart[(g * 8 + cch) * 2 + 1];
    }
    float mean = s * (1.0f / 65536.0f);
    float var  = fmaxf(ss * (1.0f / 65536.0f) - mean * mean, 0.0f);
    gmean[t] = mean;
    grstd[t] = rsqrtf(var + 1e-6f);
  }
  __syncthreads();
  {
    const int tx = t & 63, ty = t >> 6;  // ty 0..3
    #pragma unroll
    for (int i = 0; i < 16; ++i) {
      int cl = ty * 16 + i;
      int c = c0 + cl;
      float val = x[((size_t)(b * C_ + c)) * HW_ + hw0 + tx];
      tile[cl][tx] = (val - gmean[cl >> 4]) * grstd[cl >> 4] * gnw[c] + gnb[c];
    }
  }
  __syncthreads();
  {
    const int cx = (t & 31) * 2, ty = t >> 5;  // ty 0..7
    #pragma unroll
    for (int i = 0; i < 8; ++i) {
      int hwl = ty * 8 + i;
      unsigned pk = (unsigned)f2bf(tile[cx][hwl]) | ((unsigned)f2bf(tile[cx + 1][hwl]) << 16);
      *(unsigned*)&hT[((size_t)(b * HW_ + hw0 + hwl)) * C_ + c0 + cx] = pk;
    }
  }
}

// ---------------- generic bf16 A(MxK) @ B(NxK)^T GEMM, 64x64 tile -----------
template<int BIAS_N, int RESID>
__global__ __launch_bounds__(256, 4) void gemm_abt(
    const u16* __restrict__ A, int lda,
    const u16* __restrict__ B, int ldb, long bz,
    const float* __restrict__ bias,
    const float* __restrict__ resid,
    void* __restrict__ Dp, int ldd, long dz, int K)
{
  B += (size_t)blockIdx.z * (size_t)bz;
  const int t = threadIdx.x;
  const int m0 = blockIdx.x * 64, n0 = blockIdx.y * 64;
  const int wv = t >> 6, l = t & 63, lr = l & 15, lq = l >> 4;
  const int ro = (wv >> 1) * 32, co = (wv & 1) * 32;
  __shared__ u16 As[64][72];
  __shared__ u16 Bs[64][72];
  f32x4 acc[2][2] = {};
  const int ldr_ = t >> 2;
  const int ldc_ = (t & 3) * 16;
  for (int k0 = 0; k0 < K; k0 += 64) {
    *(uint4*)&As[ldr_][ldc_]     = *(const uint4*)(A + (size_t)(m0 + ldr_) * lda + k0 + ldc_);
    *(uint4*)&As[ldr_][ldc_ + 8] = *(const uint4*)(A + (size_t)(m0 + ldr_) * lda + k0 + ldc_ + 8);
    *(uint4*)&Bs[ldr_][ldc_]     = *(const uint4*)(B + (size_t)(n0 + ldr_) * ldb + k0 + ldc_);
    *(uint4*)&Bs[ldr_][ldc_ + 8] = *(const uint4*)(B + (size_t)(n0 + ldr_) * ldb + k0 + ldc_ + 8);
    __syncthreads();
    #pragma unroll
    for (int kk = 0; kk < 64; kk += 32) {
      bf16x8 a0 = *(const bf16x8*)&As[ro + lr][kk + lq * 8];
      bf16x8 a1 = *(const bf16x8*)&As[ro + 16 + lr][kk + lq * 8];
      bf16x8 b0 = *(const bf16x8*)&Bs[co + lr][kk + lq * 8];
      bf16x8 b1 = *(const bf16x8*)&Bs[co + 16 + lr][kk + lq * 8];
      acc[0][0] = MFMA16(a0, b0, acc[0][0], 0, 0, 0);
      acc[0][1] = MFMA16(a0, b1, acc[0][1], 0, 0, 0);
      acc[1][0] = MFMA16(a1, b0, acc[1][0], 0, 0, 0);
      acc[1][1] = MFMA16(a1, b1, acc[1][1], 0, 0, 0);
    }
    __syncthreads();
  }
  #pragma unroll
  for (int rf = 0; rf < 2; ++rf) {
    #pragma unroll
    for (int cf = 0; cf < 2; ++cf) {
      const int n = n0 + co + cf * 16 + lr;
      const float bn = BIAS_N ? bias[n] : 0.0f;
      #pragma unroll
      for (int reg = 0; reg < 4; ++reg) {
        const int m = m0 + ro + rf * 16 + lq * 4 + reg;
        float val = acc[rf][cf][reg] + (BIAS_N ? bn : bias[m]);
        if (RESID) {
          float* D = (float*)Dp + (size_t)blockIdx.z * dz;
          const float* R = resid + (size_t)blockIdx.z * dz;
          size_t idx = (size_t)m * ldd + n;
          D[idx] = val + R[idx];
        } else {
          ((u16*)Dp)[(size_t)m * ldd + n] = f2bf(val);
        }
      }
    }
  }
}

// ---------------- fused Q+K GEMM, 128x128 tile (m97 structure) --------------
__global__ __launch_bounds__(256, 2) void qkgemm_kernel(
    const u16* __restrict__ A, const u16* __restrict__ B,
    const float* __restrict__ qb, const float* __restrict__ kb,
    u16* __restrict__ qk)
{
  const int t = threadIdx.x;
  const int m0 = blockIdx.x * 128, n0 = blockIdx.y * 128;
  const int wv = t >> 6, l = t & 63, lr = l & 15, lq = l >> 4;
  const int wr = wv >> 1, wc = wv & 1;       // 2x2 waves of 64x64
  __shared__ u16 As[128][64];
  __shared__ u16 Bs[128][64];
  f32x4 acc[4][4] = {};
  for (int k0 = 0; k0 < 512; k0 += 64) {
    #pragma unroll
    for (int it = 0; it < 4; ++it) {
      const int ci = it * 256 + t;
      const int row = ci >> 3;
      const int c8 = (((ci & 7) ^ (row & 7)) << 3);
      gld_lds16(A + (size_t)(m0 + row) * 512 + k0 + c8, &As[0][0] + ci * 8);
      gld_lds16(B + (size_t)(n0 + row) * 512 + k0 + c8, &Bs[0][0] + ci * 8);
    }
    __syncthreads();
    #pragma unroll
    for (int kk = 0; kk < 64; kk += 32) {
      bf16x8 af[4], bf[4];
      #pragma unroll
      for (int fr = 0; fr < 4; ++fr)
        af[fr] = *(const bf16x8*)swz(&As[0][0], wr * 64 + fr * 16 + lr, kk + lq * 8, 64);
      #pragma unroll
      for (int fc = 0; fc < 4; ++fc)
        bf[fc] = *(const bf16x8*)swz(&Bs[0][0], wc * 64 + fc * 16 + lr, kk + lq * 8, 64);
      #pragma unroll
      for (int fr = 0; fr < 4; ++fr)
        #pragma unroll
        for (int fc = 0; fc < 4; ++fc)
          acc[fr][fc] = MFMA16(af[fr], bf[fc], acc[fr][fc], 0, 0, 0);
    }
    __syncthreads();
  }
  float bn[4];
  #pragma unroll
  for (int fc = 0; fc < 4; ++fc) {
    const int n = n0 + wc * 64 + fc * 16 + lr;
    bn[fc] = n < 512 ? qb[n] : kb[n - 512];
  }
  #pragma unroll
  for (int fr = 0; fr < 4; ++fr) {
    #pragma unroll
    for (int reg = 0; reg < 4; ++reg) {
      const int m = m0 + wr * 64 + fr * 16 + lq * 4 + reg;
      u16* orow = qk + (size_t)m * 1024 + n0 + wc * 64 + lr;
      #pragma unroll
      for (int fc = 0; fc < 4; ++fc)
        orow[fc * 16] = f2bf(acc[fr][fc][reg] + bn[fc]);
    }
  }
}

// ---------------- S-GEMM 256^2 counted-vmcnt ring + exp + rowsums (big) -----
__global__ __launch_bounds__(512, 2) void sgemm_exp256(
    const u16* __restrict__ A, const u16* __restrict__ B,
    u16* __restrict__ Pexp, float* __restrict__ rsp)
{
  const int z = blockIdx.z;
  A    += (size_t)z * (HW_ * 1024);
  B    += (size_t)z * (HW_ * 1024);
  Pexp += (size_t)z * PZ_;
  const int gi0 = z * HW_;
  const int t = threadIdx.x;
  const int wv = t >> 6, l = t & 63, lr = l & 15, lq = l >> 4;
  const int wr = wv >> 2, wc = wv & 3;        // 2M x 4N waves, wave out 128x64
  const int m0 = blockIdx.x * 256, n0 = blockIdx.y * 256;
  __shared__ u16 As[4][8192];
  __shared__ u16 Bs[4][8192];
  f32x4 acc[8][4] = {};
  const u16* Ab = A + (size_t)m0 * 1024;
  const u16* Bb = B + (size_t)n0 * 1024;
  RING_BODY(16, 1024, 1024, 0)
  // epilogue: exp2(s*scale), rowsum partial over wave's 64 cols
  const float SCL2 = 0.06376774487989831f;    // log2(e)/sqrt(512)
  #pragma unroll
  for (int fr = 0; fr < 8; ++fr) {
    #pragma unroll
    for (int reg = 0; reg < 4; ++reg) {
      float rsum = 0.0f;
      const int row = m0 + wr * 128 + fr * 16 + lq * 4 + reg;
      u16* prow = Pexp + (size_t)row * 4096 + n0 + wc * 64 + lr;
      #pragma unroll
      for (int fc = 0; fc < 4; ++fc) {
        float p = exp2f(acc[fr][fc][reg] * SCL2);
        rsum += p;
        prow[fc * 16] = f2bf(p);
      }
      rsum += __shfl_xor(rsum, 1);
      rsum += __shfl_xor(rsum, 2);
      rsum += __shfl_xor(rsum, 4);
      rsum += __shfl_xor(rsum, 8);
      if (lr == 0)
        rsp[(size_t)(blockIdx.y * 4 + wc) * NTOK + gi0 + row] = rsum;
    }
  }
}

// ---------------- PV GEMM 256^2 counted-vmcnt ring, split-K=4 (big) ---------
__global__ __launch_bounds__(512, 2) void pvgemm256(
    const u16* __restrict__ A, const u16* __restrict__ B, u16* __restrict__ Op)
{
  const int z = blockIdx.z;
  const int sp = z & 3, bb = z >> 2;
  A  += (size_t)bb * PZ_;
  B  += (size_t)bb * HW_;
  Op += (size_t)sp * 4194304 + (size_t)bb * 2097152;
  const int t = threadIdx.x;
  const int wv = t >> 6, l = t & 63, lr = l & 15, lq = l >> 4;
  const int wr = wv >> 2, wc = wv & 3;
  const int m0 = blockIdx.x * 256, n0 = blockIdx.y * 256;
  __shared__ u16 As[4][8192];
  __shared__ u16 Bs[4][8192];
  f32x4 acc[8][4] = {};
  const u16* Ab = A + (size_t)m0 * 4096;
  const u16* Bb = B + (size_t)n0 * NTOK;
  const int kbeg = sp * 1024;
  RING_BODY(32, 4096, NTOK, kbeg)
  #pragma unroll
  for (int fr = 0; fr < 8; ++fr) {
    #pragma unroll
    for (int reg = 0; reg < 4; ++reg) {
      const int m = m0 + wr * 128 + fr * 16 + lq * 4 + reg;
      u16* orow = Op + (size_t)m * 512 + n0 + wc * 64 + lr;
      #pragma unroll
      for (int fc = 0; fc < 4; ++fc)
        orow[fc * 16] = f2bf(acc[fr][fc][reg]);
    }
  }
}

// ---------------- fallback 128^2 kernels (proven R9 path) -------------------
__global__ __launch_bounds__(256, 2) void sgemm_exp_kernel(
    const u16* __restrict__ A, const u16* __restrict__ B,
    u16* __restrict__ Pexp, float* __restrict__ rsp, long pz, int gi0base)
{
  const int z = blockIdx.z;
  A    += (size_t)z * (HW_ * 1024);
  B    += (size_t)z * (HW_ * 1024);
  Pexp += (size_t)z * pz;
  const int gi0 = gi0base + z * HW_;
  const int t = threadIdx.x;
  const int m0 = blockIdx.x * 128, n0 = blockIdx.y * 128;
  const int wv = t >> 6, l = t & 63, lr = l & 15, lq = l >> 4;
  const int wr = wv >> 1, wc = wv & 1;
  __shared__ u16 As[128][64];
  __shared__ u16 Bs[128][64];
  f32x4 acc[4][4] = {};
  for (int k0 = 0; k0 < 512; k0 += 64) {
    #pragma unroll
    for (int it = 0; it < 4; ++it) {
      const int ci = it * 256 + t;
      const int row = ci >> 3;
      const int c8 = (((ci & 7) ^ (row & 7)) << 3);
      gld_lds16(A + (size_t)(m0 + row) * 1024 + k0 + c8, &As[0][0] + ci * 8);
      gld_lds16(B + (size_t)(n0 + row) * 1024 + k0 + c8, &Bs[0][0] + ci * 8);
    }
    __syncthreads();
    #pragma unroll
    for (int kk = 0; kk < 64; kk += 32) {
      bf16x8 af[4], bf[4];
      #pragma unroll
      for (int fr = 0; fr < 4; ++fr)
        af[fr] = *(const bf16x8*)swz(&As[0][0], wr * 64 + fr * 16 + lr, kk + lq * 8, 64);
      #pragma unroll
      for (int fc = 0; fc < 4; ++fc)
        bf[fc] = *(const bf16x8*)swz(&Bs[0][0], wc * 64 + fc * 16 + lr, kk + lq * 8, 64);
      #pragma unroll
      for (int fr = 0; fr < 4; ++fr)
        #pragma unroll
        for (int fc = 0; fc < 4; ++fc)
          acc[fr][fc] = MFMA16(af[fr], bf[fc], acc[fr][fc], 0, 0, 0);
    }
    __syncthreads();
  }
  const float SCL2 = 0.06376774487989831f;
  #pragma unroll
  for (int fr = 0; fr < 4; ++fr) {
    #pragma unroll
    for (int reg = 0; reg < 4; ++reg) {
      float rsum = 0.0f;
      const int row = m0 + wr * 64 + fr * 16 + lq * 4 + reg;
      u16* prow = Pexp + (size_t)row * 4096 + n0 + wc * 64 + lr;
      #pragma unroll
      for (int fc = 0; fc < 4; ++fc) {
        float p = exp2f(acc[fr][fc][reg] * SCL2);
        rsum += p;
        prow[fc * 16] = f2bf(p);
      }
      rsum += __shfl_xor(rsum, 1);
      rsum += __shfl_xor(rsum, 2);
      rsum += __shfl_xor(rsum, 4);
      rsum += __shfl_xor(rsum, 8);
      if (lr == 0)
        rsp[(size_t)(blockIdx.y * 2 + wc) * NTOK + gi0 + row] = rsum;
    }
  }
}

__global__ __launch_bounds__(256, 4) void pvgemm_splitk(
    const u16* __restrict__ A, const u16* __restrict__ B,
    u16* __restrict__ Op, long spstride, int logsplit)
{
  const int z = blockIdx.z;
  const int sp = z & ((1 << logsplit) - 1);
  const int bb = z >> logsplit;
  A  += (size_t)bb * PZ_;
  B  += (size_t)bb * HW_;
  Op += (size_t)sp * spstride + (size_t)bb * 2097152;
  const int t = threadIdx.x;
  const int m0 = blockIdx.x * 128, n0 = blockIdx.y * 128;
  const int wv = t >> 6, l = t & 63, lr = l & 15, lq = l >> 4;
  const int wr = wv >> 1, wc = wv & 1;
  __shared__ u16 As[128][64];
  __shared__ u16 Bs[128][64];
  f32x4 acc[4][4] = {};
  const int ksize = 4096 >> logsplit;
  const int kbeg = sp * ksize;
  for (int k0 = kbeg; k0 < kbeg + ksize; k0 += 64) {
    #pragma unroll
    for (int it = 0; it < 4; ++it) {
      const int ci = it * 256 + t;
      const int row = ci >> 3;
      const int c8 = (((ci & 7) ^ (row & 7)) << 3);
      gld_lds16(A + (size_t)(m0 + row) * 4096 + k0 + c8, &As[0][0] + ci * 8);
      gld_lds16(B + (size_t)(n0 + row) * NTOK + k0 + c8, &Bs[0][0] + ci * 8);
    }
    __syncthreads();
    #pragma unroll
    for (int kk = 0; kk < 64; kk += 32) {
      bf16x8 af[4], bf[4];
      #pragma unroll
      for (int fr = 0; fr < 4; ++fr)
        af[fr] = *(const bf16x8*)swz(&As[0][0], wr * 64 + fr * 16 + lr, kk + lq * 8, 64);
      #pragma unroll
      for (int fc = 0; fc < 4; ++fc)
        bf[fc] = *(const bf16x8*)swz(&Bs[0][0], wc * 64 + fc * 16 + lr, kk + lq * 8, 64);
      #pragma unroll
      for (int fr = 0; fr < 4; ++fr)
        #pragma unroll
        for (int fc = 0; fc < 4; ++fc)
          acc[fr][fc] = MFMA16(af[fr], bf[fc], acc[fr][fc], 0, 0, 0);
    }
    __syncthreads();
  }
  #pragma unroll
  for (int fr = 0; fr < 4; ++fr) {
    #pragma unroll
    for (int reg = 0; reg < 4; ++reg) {
      const int m = m0 + wr * 64 + fr * 16 + lq * 4 + reg;
      u16* orow = Op + (size_t)m * 512 + n0 + wc * 64 + lr;
      #pragma unroll
      for (int fc = 0; fc < 4; ++fc)
        orow[fc * 16] = f2bf(acc[fr][fc][reg]);
    }
  }
}

// ---------------- combine split-K partials + rowsum-normalize (folded) ------
__global__ __launch_bounds__(256) void combine_norm(const u16* __restrict__ Op,
                                                    const float* __restrict__ rsp,
                                                    u16* __restrict__ ao,
                                                    long spstride, int nsplit, int gi0) {
  const int t = threadIdx.x;
  __shared__ float rinvs[4];
  {
    const int tokl = t >> 6, jg = t & 63;
    float s = rsp[(size_t)jg * NTOK + gi0 + blockIdx.x * 4 + tokl];
    #pragma unroll
    for (int m = 1; m < 64; m <<= 1) s += __shfl_xor(s, m);
    if (jg == 0) rinvs[tokl] = 1.0f / s;
  }
  __syncthreads();
  const size_t idx8 = ((size_t)blockIdx.x * 256 + t) * 8;
  const float ri = rinvs[t >> 6];
  float v[8] = {};
  for (int s = 0; s < nsplit; ++s) {
    const u16* p = Op + (size_t)s * spstride + idx8;
    ushort4 a0 = *(const ushort4*)p;
    ushort4 a1 = *(const ushort4*)(p + 4);
    v[0] += bf2f(a0.x); v[1] += bf2f(a0.y); v[2] += bf2f(a0.z); v[3] += bf2f(a0.w);
    v[4] += bf2f(a1.x); v[5] += bf2f(a1.y); v[6] += bf2f(a1.z); v[7] += bf2f(a1.w);
  }
  ushort4 o0, o1;
  o0.x = f2bf(v[0] * ri); o0.y = f2bf(v[1] * ri);
  o0.z = f2bf(v[2] * ri); o0.w = f2bf(v[3] * ri);
  o1.x = f2bf(v[4] * ri); o1.y = f2bf(v[5] * ri);
  o1.z = f2bf(v[6] * ri); o1.w = f2bf(v[7] * ri);
  *(ushort4*)(ao + idx8)     = o0;
  *(ushort4*)(ao + idx8 + 4) = o1;
}

extern "C" void kernel_launch(void* const* d_in, const int* in_sizes, int n_in,
                              void* d_out, int out_size, void* d_ws, size_t ws_size,
                              hipStream_t stream) {
  const float* x   = (const float*)d_in[0];
  const float* gnw = (const float*)d_in[1];
  const float* gnb = (const float*)d_in[2];
  const float* qw  = (const float*)d_in[3];
  const float* qb  = (const float*)d_in[4];
  const float* kw  = (const float*)d_in[5];
  const float* kb  = (const float*)d_in[6];
  const float* vw  = (const float*)d_in[7];
  const float* vb  = (const float*)d_in[8];
  const float* pw  = (const float*)d_in[9];
  const float* pb  = (const float*)d_in[10];

  char* ws = (char*)d_ws;
  u16*   wqb   = (u16*)(ws + 0);             // wq then wk rows: [1024][512] bf16
  u16*   wkb   = wqb + 262144;
  u16*   wvb   = wkb + 262144;
  u16*   wpb   = wvb + 262144;
  float* rsp   = (float*)(ws + 2130432);     // [64][8192] f32 (2MB)
  float* gpart = rsp;                        // gn partials alias rsp (pre-sgemm)
  u16*   hT    = (u16*)(ws + 4227584);       // [8192][512] bf16, dead after v-GEMM
  u16*   ao    = hT;                         // reuse: [2][4096][512] bf16
  u16*   qk    = (u16*)(ws + 12616192);      // [8192][1024] bf16 (q|k per row)
  u16*   vm    = (u16*)(ws + 29393408);      // [512][8192] bf16

  const bool big = ws_size >= 138445312ULL;
  u16* OpB   = (u16*)(ws + 37782016);        // [4][2][4096][512] bf16 (33.5MB)
  u16* PexpB = (u16*)(ws + 71336448);        // [2][4096][4096] bf16 (67MB)
  u16* PexpS = (u16*)(ws + 37782016);        // fallback: [4096][4096] bf16

  wcast_kernel<<<1024, 256, 0, stream>>>(qw, kw, vw, pw, wqb);
  gn_stats1_kernel<<<dim3(64, 8), 256, 0, stream>>>(x, gpart);
  gn_apply_kernel<<<dim3(64, 8, 2), 256, 0, stream>>>(x, gnw, gnb, gpart, hT);
  qkgemm_kernel<<<dim3(64, 8), 256, 0, stream>>>(hT, wqb, qb, kb, qk);
  gemm_abt<0, 0><<<dim3(8, 128), 256, 0, stream>>>(wvb, 512, hT, 512, 0, vb, nullptr, vm, 8192, 0, 512);

  if (big) {
    sgemm_exp256<<<dim3(16, 16, 2), 512, 0, stream>>>(qk, qk + 512, PexpB, rsp);
    pvgemm256<<<dim3(16, 2, 8), 512, 0, stream>>>(PexpB, vm, OpB);
    combine_norm<<<2048, 256, 0, stream>>>(OpB, rsp, ao, 4194304L, 4, 0);
  } else {
    for (int b = 0; b < 2; ++b) {
      const u16* qkb = qk + (size_t)b * HW_ * 1024;
      sgemm_exp_kernel<<<dim3(32, 32, 1), 256, 0, stream>>>(qkb, qkb + 512, PexpS, rsp, 0L, b * HW_);
      pvgemm_splitk<<<dim3(32, 4, 2), 256, 0, stream>>>(PexpS, vm + (size_t)b * HW_, qk, 2097152L, 1);
      combine_norm<<<1024, 256, 0, stream>>>(qk, rsp, ao + (size_t)b * HW_ * C_, 2097152L, 2, b * HW_);
    }
  }
  gemm_abt<0, 1><<<dim3(8, 64, 2), 256, 0, stream>>>(wpb, 512, ao, 512, 2097152L, pb, x, d_out, 4096, 2097152L, 512);
}

// Round 11
// 147.318 us; speedup vs baseline: 1.1923x; 1.1923x over previous
//
#include <hip/hip_runtime.h>

#define C_   512
#define HW_  4096
#define NTOK 8192
#define PZ_  16777216L   // Pexp batch stride (elems) in big mode

typedef __attribute__((ext_vector_type(8))) short bf16x8;
typedef __attribute__((ext_vector_type(4))) float f32x4;
typedef unsigned short u16;

#define MFMA16 __builtin_amdgcn_mfma_f32_16x16x32_bf16

__device__ __forceinline__ u16 f2bf(float f) {
  unsigned int u = __float_as_uint(f);
  u += 0x7fffu + ((u >> 16) & 1u);
  return (u16)(u >> 16);
}

__device__ __forceinline__ float bf2f(u16 v) {
  return __uint_as_float((unsigned)v << 16);
}

__device__ __forceinline__ void gld_lds16(const u16* g, u16* l) {
  __builtin_amdgcn_global_load_lds(
      (const __attribute__((address_space(1))) void*)g,
      (__attribute__((address_space(3))) void*)l, 16, 0, 0);
}

// swizzled LDS chunk address: logical (row, u16-col) -> physical u16 offset.
// Layout: within each row (8 chunks of 16B), chunk o stored at o ^ (row&7).
// Paired with inverse-swizzled global source in the staging loop.
__device__ __forceinline__ const u16* swz(const u16* base, int row, int col, int ldu16) {
  return base + (size_t)row * ldu16 + ((((col >> 3) ^ (row & 7)) << 3) | (col & 7));
}

// ---------------- head: wcast (bid<1024) + gn_stats1 (bid>=1024) ------------
__global__ __launch_bounds__(256) void head_kernel(
    const float* __restrict__ qw, const float* __restrict__ kw,
    const float* __restrict__ vw, const float* __restrict__ pw,
    u16* __restrict__ wout, const float* __restrict__ x,
    float* __restrict__ gpart) {
  const int bid = blockIdx.x;
  const int t = threadIdx.x;
  if (bid < 1024) {
    int gid = bid * 256 + t;
    int which = gid >> 16;
    const float* src = which == 0 ? qw : which == 1 ? kw : which == 2 ? vw : pw;
    int loc = (gid & 65535) * 4;
    float4 v = *(const float4*)(src + loc);
    ushort4 o;
    o.x = f2bf(v.x); o.y = f2bf(v.y); o.z = f2bf(v.z); o.w = f2bf(v.w);
    *(ushort4*)(wout + ((size_t)which << 18) + loc) = o;
    return;
  }
  const int gb = bid - 1024;          // 512 blocks: group = gb>>3, chunk = gb&7
  const float4* p = (const float4*)(x + (size_t)(gb >> 3) * 65536 + (gb & 7) * 8192);
  float s = 0.0f, ss = 0.0f;
  for (int i = t; i < 2048; i += 256) {
    float4 v = p[i];
    s  += v.x + v.y + v.z + v.w;
    ss += v.x * v.x + v.y * v.y + v.z * v.z + v.w * v.w;
  }
  #pragma unroll
  for (int m = 1; m < 64; m <<= 1) { s += __shfl_xor(s, m); ss += __shfl_xor(ss, m); }
  __shared__ float rs[4], rss[4];
  const int wv = t >> 6;
  if ((t & 63) == 0) { rs[wv] = s; rss[wv] = ss; }
  __syncthreads();
  if (t == 0) {
    gpart[gb * 2]     = rs[0] + rs[1] + rs[2] + rs[3];
    gpart[gb * 2 + 1] = rss[0] + rss[1] + rss[2] + rss[3];
  }
}

// ---------------- GN apply (stage2 folded) + transpose to hT[8192][512] -----
__global__ __launch_bounds__(256) void gn_apply_kernel(const float* __restrict__ x,
                                                       const float* __restrict__ gnw,
                                                       const float* __restrict__ gnb,
                                                       const float* __restrict__ gpart,
                                                       u16* __restrict__ hT) {
  const int b = blockIdx.z, c0 = blockIdx.y * 64, hw0 = blockIdx.x * 64;
  const int t = threadIdx.x;
  __shared__ float tile[64][65];
  __shared__ float gmean[4], grstd[4];
  if (t < 4) {
    const int g = b * 32 + (c0 >> 4) + t;
    float s = 0.0f, ss = 0.0f;
    #pragma unroll
    for (int cch = 0; cch < 8; ++cch) {
      s  += gpart[(g * 8 + cch) * 2];
      ss += gpart[(g * 8 + cch) * 2 + 1];
    }
    float mean = s * (1.0f / 65536.0f);
    float var  = fmaxf(ss * (1.0f / 65536.0f) - mean * mean, 0.0f);
    gmean[t] = mean;
    grstd[t] = rsqrtf(var + 1e-6f);
  }
  __syncthreads();
  {
    const int tx = t & 63, ty = t >> 6;  // ty 0..3
    #pragma unroll
    for (int i = 0; i < 16; ++i) {
      int cl = ty * 16 + i;
      int c = c0 + cl;
      float val = x[((size_t)(b * C_ + c)) * HW_ + hw0 + tx];
      tile[cl][tx] = (val - gmean[cl >> 4]) * grstd[cl >> 4] * gnw[c] + gnb[c];
    }
  }
  __syncthreads();
  {
    const int cx = (t & 31) * 2, ty = t >> 5;  // ty 0..7
    #pragma unroll
    for (int i = 0; i < 8; ++i) {
      int hwl = ty * 8 + i;
      unsigned pk = (unsigned)f2bf(tile[cx][hwl]) | ((unsigned)f2bf(tile[cx + 1][hwl]) << 16);
      *(unsigned*)&hT[((size_t)(b * HW_ + hw0 + hwl)) * C_ + c0 + cx] = pk;
    }
  }
}

// ---------------- generic bf16 A(MxK) @ B(NxK)^T GEMM, 64x64 tile -----------
// BIAS_N: bias indexed by n (else by m). RESID: fp32 out + residual add.
template<int BIAS_N, int RESID>
__global__ __launch_bounds__(256, 4) void gemm_abt(
    const u16* __restrict__ A, int lda,
    const u16* __restrict__ B, int ldb, long bz,
    const float* __restrict__ bias,
    const float* __restrict__ resid,
    void* __restrict__ Dp, int ldd, long dz, int K)
{
  B += (size_t)blockIdx.z * (size_t)bz;
  const int t = threadIdx.x;
  const int m0 = blockIdx.x * 64, n0 = blockIdx.y * 64;
  const int wv = t >> 6, l = t & 63, lr = l & 15, lq = l >> 4;
  const int ro = (wv >> 1) * 32, co = (wv & 1) * 32;
  __shared__ u16 As[64][72];
  __shared__ u16 Bs[64][72];
  f32x4 acc[2][2] = {};
  const int ldr_ = t >> 2;
  const int ldc_ = (t & 3) * 16;
  for (int k0 = 0; k0 < K; k0 += 64) {
    *(uint4*)&As[ldr_][ldc_]     = *(const uint4*)(A + (size_t)(m0 + ldr_) * lda + k0 + ldc_);
    *(uint4*)&As[ldr_][ldc_ + 8] = *(const uint4*)(A + (size_t)(m0 + ldr_) * lda + k0 + ldc_ + 8);
    *(uint4*)&Bs[ldr_][ldc_]     = *(const uint4*)(B + (size_t)(n0 + ldr_) * ldb + k0 + ldc_);
    *(uint4*)&Bs[ldr_][ldc_ + 8] = *(const uint4*)(B + (size_t)(n0 + ldr_) * ldb + k0 + ldc_ + 8);
    __syncthreads();
    #pragma unroll
    for (int kk = 0; kk < 64; kk += 32) {
      bf16x8 a0 = *(const bf16x8*)&As[ro + lr][kk + lq * 8];
      bf16x8 a1 = *(const bf16x8*)&As[ro + 16 + lr][kk + lq * 8];
      bf16x8 b0 = *(const bf16x8*)&Bs[co + lr][kk + lq * 8];
      bf16x8 b1 = *(const bf16x8*)&Bs[co + 16 + lr][kk + lq * 8];
      acc[0][0] = MFMA16(a0, b0, acc[0][0], 0, 0, 0);
      acc[0][1] = MFMA16(a0, b1, acc[0][1], 0, 0, 0);
      acc[1][0] = MFMA16(a1, b0, acc[1][0], 0, 0, 0);
      acc[1][1] = MFMA16(a1, b1, acc[1][1], 0, 0, 0);
    }
    __syncthreads();
  }
  #pragma unroll
  for (int rf = 0; rf < 2; ++rf) {
    #pragma unroll
    for (int cf = 0; cf < 2; ++cf) {
      const int n = n0 + co + cf * 16 + lr;
      const float bn = BIAS_N ? bias[n] : 0.0f;
      #pragma unroll
      for (int reg = 0; reg < 4; ++reg) {
        const int m = m0 + ro + rf * 16 + lq * 4 + reg;
        float val = acc[rf][cf][reg] + (BIAS_N ? bn : bias[m]);
        if (RESID) {
          float* D = (float*)Dp + (size_t)blockIdx.z * dz;
          const float* R = resid + (size_t)blockIdx.z * dz;
          size_t idx = (size_t)m * ldd + n;
          D[idx] = val + R[idx];
        } else {
          ((u16*)Dp)[(size_t)m * ldd + n] = f2bf(val);
        }
      }
    }
  }
}

// ---------------- merged QKV GEMM, 128x128 tiles, one dispatch --------------
// bid < 512: qk part. A=hT rows, B=wqkb rows [1024][512], out qk[8192][1024],
//            bias n<512 ? qb : kb. grid decode: mt=bid>>3 (64), nt=bid&7 (8).
// bid >= 512: v part. A=wvb rows [512][512], B=hT rows, out vm[512][8192],
//            bias per-m. decode: mt=(bid-512)>>6 (4), nt=(bid-512)&63 (64).
__global__ __launch_bounds__(256, 4) void qkv_kernel(
    const u16* __restrict__ hT, const u16* __restrict__ wqkb,
    const u16* __restrict__ wvb,
    const float* __restrict__ qb, const float* __restrict__ kb,
    const float* __restrict__ vb,
    u16* __restrict__ qk, u16* __restrict__ vm)
{
  const int bid = blockIdx.x;
  const int t = threadIdx.x;
  const int wv = t >> 6, l = t & 63, lr = l & 15, lq = l >> 4;
  const int wr = wv >> 1, wc = wv & 1;       // 2x2 waves of 64x64
  const bool isqk = bid < 512;
  const int m0 = isqk ? (bid >> 3) * 128 : ((bid - 512) >> 6) * 128;
  const int n0 = isqk ? (bid & 7) * 128  : ((bid - 512) & 63) * 128;
  const u16* Arow = (isqk ? hT : wvb) + (size_t)m0 * 512;
  const u16* Brow = (isqk ? wqkb : hT) + (size_t)n0 * 512;
  __shared__ u16 As[128][64];
  __shared__ u16 Bs[128][64];
  f32x4 acc[4][4] = {};
  for (int k0 = 0; k0 < 512; k0 += 64) {
    #pragma unroll
    for (int it = 0; it < 4; ++it) {
      const int ci = it * 256 + t;           // 1024 chunks of 16B
      const int row = ci >> 3;
      const int c8 = (((ci & 7) ^ (row & 7)) << 3);  // inverse-swizzled src octet
      gld_lds16(Arow + (size_t)row * 512 + k0 + c8, &As[0][0] + ci * 8);
      gld_lds16(Brow + (size_t)row * 512 + k0 + c8, &Bs[0][0] + ci * 8);
    }
    __syncthreads();
    #pragma unroll
    for (int kk = 0; kk < 64; kk += 32) {
      bf16x8 af[4], bf[4];
      #pragma unroll
      for (int fr = 0; fr < 4; ++fr)
        af[fr] = *(const bf16x8*)swz(&As[0][0], wr * 64 + fr * 16 + lr, kk + lq * 8, 64);
      #pragma unroll
      for (int fc = 0; fc < 4; ++fc)
        bf[fc] = *(const bf16x8*)swz(&Bs[0][0], wc * 64 + fc * 16 + lr, kk + lq * 8, 64);
      #pragma unroll
      for (int fr = 0; fr < 4; ++fr)
        #pragma unroll
        for (int fc = 0; fc < 4; ++fc)
          acc[fr][fc] = MFMA16(af[fr], bf[fc], acc[fr][fc], 0, 0, 0);
    }
    __syncthreads();
  }
  if (isqk) {
    float bn[4];
    #pragma unroll
    for (int fc = 0; fc < 4; ++fc) {
      const int n = n0 + wc * 64 + fc * 16 + lr;
      bn[fc] = n < 512 ? qb[n] : kb[n - 512];
    }
    #pragma unroll
    for (int fr = 0; fr < 4; ++fr) {
      #pragma unroll
      for (int reg = 0; reg < 4; ++reg) {
        const int m = m0 + wr * 64 + fr * 16 + lq * 4 + reg;
        u16* orow = qk + (size_t)m * 1024 + n0 + wc * 64 + lr;
        #pragma unroll
        for (int fc = 0; fc < 4; ++fc)
          orow[fc * 16] = f2bf(acc[fr][fc][reg] + bn[fc]);
      }
    }
  } else {
    #pragma unroll
    for (int fr = 0; fr < 4; ++fr) {
      #pragma unroll
      for (int reg = 0; reg < 4; ++reg) {
        const int m = m0 + wr * 64 + fr * 16 + lq * 4 + reg;
        const float bm = vb[m];
        u16* orow = vm + (size_t)m * NTOK + n0 + wc * 64 + lr;
        #pragma unroll
        for (int fc = 0; fc < 4; ++fc)
          orow[fc * 16] = f2bf(acc[fr][fc][reg] + bm);
      }
    }
  }
}

// ---------------- S-GEMM + exp + rowsum partials (m97 structure) ------------
// z = batch (big) or 0 (fallback; host pre-offsets). A,B = qk slices,
// lda/ldb = 1024 (q = cols 0..511, k = cols 512..1023). Tile 128x128, BK=64.
__global__ __launch_bounds__(256, 2) void sgemm_exp_kernel(
    const u16* __restrict__ A, const u16* __restrict__ B,
    u16* __restrict__ Pexp, float* __restrict__ rsp, long pz, int gi0base)
{
  const int z = blockIdx.z;
  A    += (size_t)z * (HW_ * 1024);
  B    += (size_t)z * (HW_ * 1024);
  Pexp += (size_t)z * pz;
  const int gi0 = gi0base + z * HW_;
  const int t = threadIdx.x;
  const int m0 = blockIdx.x * 128, n0 = blockIdx.y * 128;
  const int wv = t >> 6, l = t & 63, lr = l & 15, lq = l >> 4;
  const int wr = wv >> 1, wc = wv & 1;       // 2x2 waves of 64x64
  __shared__ u16 As[128][64];
  __shared__ u16 Bs[128][64];
  f32x4 acc[4][4] = {};
  for (int k0 = 0; k0 < 512; k0 += 64) {
    #pragma unroll
    for (int it = 0; it < 4; ++it) {
      const int ci = it * 256 + t;           // 1024 chunks of 16B
      const int row = ci >> 3;
      const int c8 = (((ci & 7) ^ (row & 7)) << 3);  // inverse-swizzled src octet
      gld_lds16(A + (size_t)(m0 + row) * 1024 + k0 + c8, &As[0][0] + ci * 8);
      gld_lds16(B + (size_t)(n0 + row) * 1024 + k0 + c8, &Bs[0][0] + ci * 8);
    }
    __syncthreads();
    #pragma unroll
    for (int kk = 0; kk < 64; kk += 32) {
      bf16x8 af[4], bf[4];
      #pragma unroll
      for (int fr = 0; fr < 4; ++fr)
        af[fr] = *(const bf16x8*)swz(&As[0][0], wr * 64 + fr * 16 + lr, kk + lq * 8, 64);
      #pragma unroll
      for (int fc = 0; fc < 4; ++fc)
        bf[fc] = *(const bf16x8*)swz(&Bs[0][0], wc * 64 + fc * 16 + lr, kk + lq * 8, 64);
      #pragma unroll
      for (int fr = 0; fr < 4; ++fr)
        #pragma unroll
        for (int fc = 0; fc < 4; ++fc)
          acc[fr][fc] = MFMA16(af[fr], bf[fc], acc[fr][fc], 0, 0, 0);
    }
    __syncthreads();
  }
  // epilogue: exp2(s*scale), rowsum partial over this wave's 64 cols, stores
  const float SCL2 = 0.06376774487989831f;   // log2(e)/sqrt(512)
  #pragma unroll
  for (int fr = 0; fr < 4; ++fr) {
    #pragma unroll
    for (int reg = 0; reg < 4; ++reg) {
      float rsum = 0.0f;
      const int row = m0 + wr * 64 + fr * 16 + lq * 4 + reg;
      u16* prow = Pexp + (size_t)row * 4096 + n0 + wc * 64 + lr;
      #pragma unroll
      for (int fc = 0; fc < 4; ++fc) {
        float p = exp2f(acc[fr][fc][reg] * SCL2);
        rsum += p;
        prow[fc * 16] = f2bf(p);
      }
      rsum += __shfl_xor(rsum, 1);
      rsum += __shfl_xor(rsum, 2);
      rsum += __shfl_xor(rsum, 4);
      rsum += __shfl_xor(rsum, 8);
      if (lr == 0)
        rsp[(size_t)(blockIdx.y * 2 + wc) * NTOK + gi0 + row] = rsum;
    }
  }
}

// ---------------- PV GEMM split-K, 128x128 tile (m97 2:1 MFMA:ds ratio) -----
// z encodes (split, batch): sp = z & (nsplit-1), bb = z >> logsplit.
// A=Pexp [4096][4096]; B=vm channel-major rows [512][tok]. BK=64.
// Op elem offset = sp*spstride + bb*2097152.
__global__ __launch_bounds__(256, 4) void pvgemm_splitk(
    const u16* __restrict__ A, const u16* __restrict__ B,
    u16* __restrict__ Op, long spstride, int logsplit)
{
  const int z = blockIdx.z;
  const int sp = z & ((1 << logsplit) - 1);
  const int bb = z >> logsplit;
  A  += (size_t)bb * PZ_;
  B  += (size_t)bb * HW_;
  Op += (size_t)sp * spstride + (size_t)bb * 2097152;
  const int t = threadIdx.x;
  const int m0 = blockIdx.x * 128, n0 = blockIdx.y * 128;
  const int wv = t >> 6, l = t & 63, lr = l & 15, lq = l >> 4;
  const int wr = wv >> 1, wc = wv & 1;       // 2x2 waves of 64x64
  __shared__ u16 As[128][64];
  __shared__ u16 Bs[128][64];
  f32x4 acc[4][4] = {};
  const int ksize = 4096 >> logsplit;
  const int kbeg = sp * ksize;
  for (int k0 = kbeg; k0 < kbeg + ksize; k0 += 64) {
    #pragma unroll
    for (int it = 0; it < 4; ++it) {
      const int ci = it * 256 + t;           // 1024 chunks of 16B per buffer
      const int row = ci >> 3;
      const int c8 = (((ci & 7) ^ (row & 7)) << 3);  // inverse-swizzled src octet
      gld_lds16(A + (size_t)(m0 + row) * 4096 + k0 + c8, &As[0][0] + ci * 8);
      gld_lds16(B + (size_t)(n0 + row) * NTOK + k0 + c8, &Bs[0][0] + ci * 8);
    }
    __syncthreads();
    #pragma unroll
    for (int kk = 0; kk < 64; kk += 32) {
      bf16x8 af[4], bf[4];
      #pragma unroll
      for (int fr = 0; fr < 4; ++fr)
        af[fr] = *(const bf16x8*)swz(&As[0][0], wr * 64 + fr * 16 + lr, kk + lq * 8, 64);
      #pragma unroll
      for (int fc = 0; fc < 4; ++fc)
        bf[fc] = *(const bf16x8*)swz(&Bs[0][0], wc * 64 + fc * 16 + lr, kk + lq * 8, 64);
      #pragma unroll
      for (int fr = 0; fr < 4; ++fr)
        #pragma unroll
        for (int fc = 0; fc < 4; ++fc)
          acc[fr][fc] = MFMA16(af[fr], bf[fc], acc[fr][fc], 0, 0, 0);
    }
    __syncthreads();
  }
  #pragma unroll
  for (int fr = 0; fr < 4; ++fr) {
    #pragma unroll
    for (int reg = 0; reg < 4; ++reg) {
      const int m = m0 + wr * 64 + fr * 16 + lq * 4 + reg;
      u16* orow = Op + (size_t)m * 512 + n0 + wc * 64 + lr;
      #pragma unroll
      for (int fc = 0; fc < 4; ++fc)
        orow[fc * 16] = f2bf(acc[fr][fc][reg]);
    }
  }
}

// ---------------- combine split-K partials + rowsum-normalize (folded) ------
// Block covers 2048 elems = 4 tokens. Wave w computes rinv for its token by
// reducing the 64 rowsum partials, then all threads combine nsplit partials.
__global__ __launch_bounds__(256) void combine_norm(const u16* __restrict__ Op,
                                                    const float* __restrict__ rsp,
                                                    u16* __restrict__ ao,
                                                    long spstride, int nsplit, int gi0) {
  const int t = threadIdx.x;
  __shared__ float rinvs[4];
  {
    const int tokl = t >> 6, jg = t & 63;
    float s = rsp[(size_t)jg * NTOK + gi0 + blockIdx.x * 4 + tokl];
    #pragma unroll
    for (int m = 1; m < 64; m <<= 1) s += __shfl_xor(s, m);
    if (jg == 0) rinvs[tokl] = 1.0f / s;
  }
  __syncthreads();
  const size_t idx8 = ((size_t)blockIdx.x * 256 + t) * 8;
  const float ri = rinvs[t >> 6];
  float v[8] = {};
  for (int s = 0; s < nsplit; ++s) {
    const u16* p = Op + (size_t)s * spstride + idx8;
    ushort4 a0 = *(const ushort4*)p;
    ushort4 a1 = *(const ushort4*)(p + 4);
    v[0] += bf2f(a0.x); v[1] += bf2f(a0.y); v[2] += bf2f(a0.z); v[3] += bf2f(a0.w);
    v[4] += bf2f(a1.x); v[5] += bf2f(a1.y); v[6] += bf2f(a1.z); v[7] += bf2f(a1.w);
  }
  ushort4 o0, o1;
  o0.x = f2bf(v[0] * ri); o0.y = f2bf(v[1] * ri);
  o0.z = f2bf(v[2] * ri); o0.w = f2bf(v[3] * ri);
  o1.x = f2bf(v[4] * ri); o1.y = f2bf(v[5] * ri);
  o1.z = f2bf(v[6] * ri); o1.w = f2bf(v[7] * ri);
  *(ushort4*)(ao + idx8)     = o0;
  *(ushort4*)(ao + idx8 + 4) = o1;
}

extern "C" void kernel_launch(void* const* d_in, const int* in_sizes, int n_in,
                              void* d_out, int out_size, void* d_ws, size_t ws_size,
                              hipStream_t stream) {
  const float* x   = (const float*)d_in[0];
  const float* gnw = (const float*)d_in[1];
  const float* gnb = (const float*)d_in[2];
  const float* qw  = (const float*)d_in[3];
  const float* qb  = (const float*)d_in[4];
  const float* kw  = (const float*)d_in[5];
  const float* kb  = (const float*)d_in[6];
  const float* vw  = (const float*)d_in[7];
  const float* vb  = (const float*)d_in[8];
  const float* pw  = (const float*)d_in[9];
  const float* pb  = (const float*)d_in[10];

  // common prefix layout (both modes)
  char* ws = (char*)d_ws;
  u16*   wqb   = (u16*)(ws + 0);             // wq then wk rows: [1024][512] bf16
  u16*   wkb   = wqb + 262144;
  u16*   wvb   = wkb + 262144;
  u16*   wpb   = wvb + 262144;
  float* rsp   = (float*)(ws + 2130432);     // [64][8192] f32 (2MB)
  float* gpart = rsp;                        // gn partials alias rsp (pre-sgemm)
  u16*   hT    = (u16*)(ws + 4227584);       // [8192][512] bf16, dead after qkv
  u16*   ao    = hT;                         // reuse: [2][4096][512] bf16
  u16*   qk    = (u16*)(ws + 12616192);      // [8192][1024] bf16 (q|k per row)
  u16*   vm    = (u16*)(ws + 29393408);      // [512][8192] bf16

  // big mode (ws >= ~138.5MB): both-batch Pexp + 4-way split-K Op partials
  const bool big = ws_size >= 138445312ULL;
  u16* OpB   = (u16*)(ws + 37782016);        // [4][2][4096][512] bf16 (33.5MB)
  u16* PexpB = (u16*)(ws + 71336448);        // [2][4096][4096] bf16 (67MB)
  // fallback (ws >= 77.66MB proven): single-batch Pexp, Op strided over qk
  u16* PexpS = (u16*)(ws + 37782016);        // [4096][4096] bf16 (33.5MB)

  head_kernel<<<1536, 256, 0, stream>>>(qw, kw, vw, pw, wqb, x, gpart);
  gn_apply_kernel<<<dim3(64, 8, 2), 256, 0, stream>>>(x, gnw, gnb, gpart, hT);
  // merged q+k (512 blocks) and v (256 blocks) in one dispatch
  qkv_kernel<<<768, 256, 0, stream>>>(hT, wqb, wvb, qb, kb, vb, qk, vm);

  if (big) {
    sgemm_exp_kernel<<<dim3(32, 32, 2), 256, 0, stream>>>(qk, qk + 512, PexpB, rsp, PZ_, 0);
    pvgemm_splitk<<<dim3(32, 4, 8), 256, 0, stream>>>(PexpB, vm, OpB, 4194304L, 2);
    combine_norm<<<2048, 256, 0, stream>>>(OpB, rsp, ao, 4194304L, 4, 0);
  } else {
    for (int b = 0; b < 2; ++b) {
      const u16* qkb = qk + (size_t)b * HW_ * 1024;
      sgemm_exp_kernel<<<dim3(32, 32, 1), 256, 0, stream>>>(qkb, qkb + 512, PexpS, rsp, 0L, b * HW_);
      pvgemm_splitk<<<dim3(32, 4, 2), 256, 0, stream>>>(PexpS, vm + (size_t)b * HW_, qk, 2097152L, 1);
      combine_norm<<<1024, 256, 0, stream>>>(qk, rsp, ao + (size_t)b * HW_ * C_, 2097152L, 2, b * HW_);
    }
  }
  // proj + bias + residual, fp32 out, per-batch via blockIdx.z
  gemm_abt<0, 1><<<dim3(8, 64, 2), 256, 0, stream>>>(wpb, 512, ao, 512, 2097152L, pb, x, d_out, 4096, 2097152L, 512);
}

// Round 12
// 144.490 us; speedup vs baseline: 1.2157x; 1.0196x over previous
//
#include <hip/hip_runtime.h>

#define C_   512
#define HW_  4096
#define NTOK 8192
#define PZ_  16777216L   // Pexp batch stride (elems) in big mode

typedef __attribute__((ext_vector_type(8))) short bf16x8;
typedef __attribute__((ext_vector_type(4))) float f32x4;
typedef unsigned short u16;

#define MFMA16 __builtin_amdgcn_mfma_f32_16x16x32_bf16

__device__ __forceinline__ u16 f2bf(float f) {
  unsigned int u = __float_as_uint(f);
  u += 0x7fffu + ((u >> 16) & 1u);
  return (u16)(u >> 16);
}

__device__ __forceinline__ float bf2f(u16 v) {
  return __uint_as_float((unsigned)v << 16);
}

__device__ __forceinline__ void gld_lds16(const u16* g, u16* l) {
  __builtin_amdgcn_global_load_lds(
      (const __attribute__((address_space(1))) void*)g,
      (__attribute__((address_space(3))) void*)l, 16, 0, 0);
}

// swizzled LDS chunk address: logical (row, u16-col) -> physical u16 offset.
__device__ __forceinline__ const u16* swz(const u16* base, int row, int col, int ldu16) {
  return base + (size_t)row * ldu16 + ((((col >> 3) ^ (row & 7)) << 3) | (col & 7));
}

// K-PERMUTED STORAGE: within each 64-wide K group, logical col g*64+f*16+r
// (f in [0,4), r in [0,16)) is STORED at g*64 + r*4 + f. Every epilogue wave
// lane holds exactly {f=0..3} for fixed r=lr -> one ushort4 store. All
// consumers pair operands positionally (both sides identically permuted), so
// MFMA k-reductions are unaffected. Applied to: qk cols, Pexp cols, vm token
// cols, Op/ao channel cols, wpb channel cols.

// ---------------- head: wcast (bid<1024) + gn_stats1 (bid>=1024) ------------
__global__ __launch_bounds__(256) void head_kernel(
    const float* __restrict__ qw, const float* __restrict__ kw,
    const float* __restrict__ vw, const float* __restrict__ pw,
    u16* __restrict__ wout, const float* __restrict__ x,
    float* __restrict__ gpart) {
  const int bid = blockIdx.x;
  const int t = threadIdx.x;
  if (bid < 1024) {
    int gid = bid * 256 + t;
    int which = gid >> 16;
    const float* src = which == 0 ? qw : which == 1 ? kw : which == 2 ? vw : pw;
    int loc = (gid & 65535) * 4;
    float4 v = *(const float4*)(src + loc);
    if (which == 3) {
      // wpb: permute channel (col) dim to match ao's stored layout
      const int row = loc >> 9, c = loc & 511;
      const int g = c & ~63, f = (c >> 4) & 3, r0 = c & 15;
      u16* base = wout + ((size_t)3 << 18) + (size_t)row * 512 + g;
      base[(r0 + 0) * 4 + f] = f2bf(v.x);
      base[(r0 + 1) * 4 + f] = f2bf(v.y);
      base[(r0 + 2) * 4 + f] = f2bf(v.z);
      base[(r0 + 3) * 4 + f] = f2bf(v.w);
    } else {
      ushort4 o;
      o.x = f2bf(v.x); o.y = f2bf(v.y); o.z = f2bf(v.z); o.w = f2bf(v.w);
      *(ushort4*)(wout + ((size_t)which << 18) + loc) = o;
    }
    return;
  }
  const int gb = bid - 1024;          // 512 blocks: group = gb>>3, chunk = gb&7
  const float4* p = (const float4*)(x + (size_t)(gb >> 3) * 65536 + (gb & 7) * 8192);
  float s = 0.0f, ss = 0.0f;
  for (int i = t; i < 2048; i += 256) {
    float4 v = p[i];
    s  += v.x + v.y + v.z + v.w;
    ss += v.x * v.x + v.y * v.y + v.z * v.z + v.w * v.w;
  }
  #pragma unroll
  for (int m = 1; m < 64; m <<= 1) { s += __shfl_xor(s, m); ss += __shfl_xor(ss, m); }
  __shared__ float rs[4], rss[4];
  const int wv = t >> 6;
  if ((t & 63) == 0) { rs[wv] = s; rss[wv] = ss; }
  __syncthreads();
  if (t == 0) {
    gpart[gb * 2]     = rs[0] + rs[1] + rs[2] + rs[3];
    gpart[gb * 2 + 1] = rss[0] + rss[1] + rss[2] + rss[3];
  }
}

// ---------------- GN apply (stage2 folded) + transpose to hT[8192][512] -----
__global__ __launch_bounds__(256) void gn_apply_kernel(const float* __restrict__ x,
                                                       const float* __restrict__ gnw,
                                                       const float* __restrict__ gnb,
                                                       const float* __restrict__ gpart,
                                                       u16* __restrict__ hT) {
  const int b = blockIdx.z, c0 = blockIdx.y * 64, hw0 = blockIdx.x * 64;
  const int t = threadIdx.x;
  __shared__ float tile[64][65];
  __shared__ float gmean[4], grstd[4];
  if (t < 4) {
    const int g = b * 32 + (c0 >> 4) + t;
    float s = 0.0f, ss = 0.0f;
    #pragma unroll
    for (int cch = 0; cch < 8; ++cch) {
      s  += gpart[(g * 8 + cch) * 2];
      ss += gpart[(g * 8 + cch) * 2 + 1];
    }
    float mean = s * (1.0f / 65536.0f);
    float var  = fmaxf(ss * (1.0f / 65536.0f) - mean * mean, 0.0f);
    gmean[t] = mean;
    grstd[t] = rsqrtf(var + 1e-6f);
  }
  __syncthreads();
  {
    const int tx = t & 63, ty = t >> 6;  // ty 0..3
    #pragma unroll
    for (int i = 0; i < 16; ++i) {
      int cl = ty * 16 + i;
      int c = c0 + cl;
      float val = x[((size_t)(b * C_ + c)) * HW_ + hw0 + tx];
      tile[cl][tx] = (val - gmean[cl >> 4]) * grstd[cl >> 4] * gnw[c] + gnb[c];
    }
  }
  __syncthreads();
  {
    const int cx = (t & 31) * 2, ty = t >> 5;  // ty 0..7
    #pragma unroll
    for (int i = 0; i < 8; ++i) {
      int hwl = ty * 8 + i;
      unsigned pk = (unsigned)f2bf(tile[cx][hwl]) | ((unsigned)f2bf(tile[cx + 1][hwl]) << 16);
      *(unsigned*)&hT[((size_t)(b * HW_ + hw0 + hwl)) * C_ + c0 + cx] = pk;
    }
  }
}

// ---------------- generic bf16 A(MxK) @ B(NxK)^T GEMM, 64x64 tile -----------
// BIAS_N: bias indexed by n (else by m). RESID: fp32 out + residual add.
template<int BIAS_N, int RESID>
__global__ __launch_bounds__(256, 4) void gemm_abt(
    const u16* __restrict__ A, int lda,
    const u16* __restrict__ B, int ldb, long bz,
    const float* __restrict__ bias,
    const float* __restrict__ resid,
    void* __restrict__ Dp, int ldd, long dz, int K)
{
  B += (size_t)blockIdx.z * (size_t)bz;
  const int t = threadIdx.x;
  const int m0 = blockIdx.x * 64, n0 = blockIdx.y * 64;
  const int wv = t >> 6, l = t & 63, lr = l & 15, lq = l >> 4;
  const int ro = (wv >> 1) * 32, co = (wv & 1) * 32;
  __shared__ u16 As[64][72];
  __shared__ u16 Bs[64][72];
  f32x4 acc[2][2] = {};
  const int ldr_ = t >> 2;
  const int ldc_ = (t & 3) * 16;
  for (int k0 = 0; k0 < K; k0 += 64) {
    *(uint4*)&As[ldr_][ldc_]     = *(const uint4*)(A + (size_t)(m0 + ldr_) * lda + k0 + ldc_);
    *(uint4*)&As[ldr_][ldc_ + 8] = *(const uint4*)(A + (size_t)(m0 + ldr_) * lda + k0 + ldc_ + 8);
    *(uint4*)&Bs[ldr_][ldc_]     = *(const uint4*)(B + (size_t)(n0 + ldr_) * ldb + k0 + ldc_);
    *(uint4*)&Bs[ldr_][ldc_ + 8] = *(const uint4*)(B + (size_t)(n0 + ldr_) * ldb + k0 + ldc_ + 8);
    __syncthreads();
    #pragma unroll
    for (int kk = 0; kk < 64; kk += 32) {
      bf16x8 a0 = *(const bf16x8*)&As[ro + lr][kk + lq * 8];
      bf16x8 a1 = *(const bf16x8*)&As[ro + 16 + lr][kk + lq * 8];
      bf16x8 b0 = *(const bf16x8*)&Bs[co + lr][kk + lq * 8];
      bf16x8 b1 = *(const bf16x8*)&Bs[co + 16 + lr][kk + lq * 8];
      acc[0][0] = MFMA16(a0, b0, acc[0][0], 0, 0, 0);
      acc[0][1] = MFMA16(a0, b1, acc[0][1], 0, 0, 0);
      acc[1][0] = MFMA16(a1, b0, acc[1][0], 0, 0, 0);
      acc[1][1] = MFMA16(a1, b1, acc[1][1], 0, 0, 0);
    }
    __syncthreads();
  }
  #pragma unroll
  for (int rf = 0; rf < 2; ++rf) {
    #pragma unroll
    for (int cf = 0; cf < 2; ++cf) {
      const int n = n0 + co + cf * 16 + lr;
      const float bn = BIAS_N ? bias[n] : 0.0f;
      #pragma unroll
      for (int reg = 0; reg < 4; ++reg) {
        const int m = m0 + ro + rf * 16 + lq * 4 + reg;
        float val = acc[rf][cf][reg] + (BIAS_N ? bn : bias[m]);
        if (RESID) {
          float* D = (float*)Dp + (size_t)blockIdx.z * dz;
          const float* R = resid + (size_t)blockIdx.z * dz;
          size_t idx = (size_t)m * ldd + n;
          D[idx] = val + R[idx];
        } else {
          ((u16*)Dp)[(size_t)m * ldd + n] = f2bf(val);
        }
      }
    }
  }
}

// ---------------- merged QKV GEMM, 128x128 tiles, one dispatch --------------
// bid < 512: qk part -> qk[8192][1024] (cols K-permuted).
// bid >= 512: v part -> vm[512][8192] (token cols K-permuted).
__global__ __launch_bounds__(256, 4) void qkv_kernel(
    const u16* __restrict__ hT, const u16* __restrict__ wqkb,
    const u16* __restrict__ wvb,
    const float* __restrict__ qb, const float* __restrict__ kb,
    const float* __restrict__ vb,
    u16* __restrict__ qk, u16* __restrict__ vm)
{
  const int bid = blockIdx.x;
  const int t = threadIdx.x;
  const int wv = t >> 6, l = t & 63, lr = l & 15, lq = l >> 4;
  const int wr = wv >> 1, wc = wv & 1;       // 2x2 waves of 64x64
  const bool isqk = bid < 512;
  const int m0 = isqk ? (bid >> 3) * 128 : ((bid - 512) >> 6) * 128;
  const int n0 = isqk ? (bid & 7) * 128  : ((bid - 512) & 63) * 128;
  const u16* Arow = (isqk ? hT : wvb) + (size_t)m0 * 512;
  const u16* Brow = (isqk ? wqkb : hT) + (size_t)n0 * 512;
  __shared__ u16 As[128][64];
  __shared__ u16 Bs[128][64];
  f32x4 acc[4][4] = {};
  for (int k0 = 0; k0 < 512; k0 += 64) {
    #pragma unroll
    for (int it = 0; it < 4; ++it) {
      const int ci = it * 256 + t;           // 1024 chunks of 16B
      const int row = ci >> 3;
      const int c8 = (((ci & 7) ^ (row & 7)) << 3);  // inverse-swizzled src octet
      gld_lds16(Arow + (size_t)row * 512 + k0 + c8, &As[0][0] + ci * 8);
      gld_lds16(Brow + (size_t)row * 512 + k0 + c8, &Bs[0][0] + ci * 8);
    }
    __syncthreads();
    #pragma unroll
    for (int kk = 0; kk < 64; kk += 32) {
      bf16x8 af[4], bf[4];
      #pragma unroll
      for (int fr = 0; fr < 4; ++fr)
        af[fr] = *(const bf16x8*)swz(&As[0][0], wr * 64 + fr * 16 + lr, kk + lq * 8, 64);
      #pragma unroll
      for (int fc = 0; fc < 4; ++fc)
        bf[fc] = *(const bf16x8*)swz(&Bs[0][0], wc * 64 + fc * 16 + lr, kk + lq * 8, 64);
      #pragma unroll
      for (int fr = 0; fr < 4; ++fr)
        #pragma unroll
        for (int fc = 0; fc < 4; ++fc)
          acc[fr][fc] = MFMA16(af[fr], bf[fc], acc[fr][fc], 0, 0, 0);
    }
    __syncthreads();
  }
  if (isqk) {
    float bn[4];
    #pragma unroll
    for (int fc = 0; fc < 4; ++fc) {
      const int n = n0 + wc * 64 + fc * 16 + lr;     // logical col for bias
      bn[fc] = n < 512 ? qb[n] : kb[n - 512];
    }
    #pragma unroll
    for (int fr = 0; fr < 4; ++fr) {
      #pragma unroll
      for (int reg = 0; reg < 4; ++reg) {
        const int m = m0 + wr * 64 + fr * 16 + lq * 4 + reg;
        ushort4 o;
        o.x = f2bf(acc[fr][0][reg] + bn[0]);
        o.y = f2bf(acc[fr][1][reg] + bn[1]);
        o.z = f2bf(acc[fr][2][reg] + bn[2]);
        o.w = f2bf(acc[fr][3][reg] + bn[3]);
        *(ushort4*)(qk + (size_t)m * 1024 + n0 + wc * 64 + lr * 4) = o;
      }
    }
  } else {
    #pragma unroll
    for (int fr = 0; fr < 4; ++fr) {
      #pragma unroll
      for (int reg = 0; reg < 4; ++reg) {
        const int m = m0 + wr * 64 + fr * 16 + lq * 4 + reg;
        const float bm = vb[m];
        ushort4 o;
        o.x = f2bf(acc[fr][0][reg] + bm);
        o.y = f2bf(acc[fr][1][reg] + bm);
        o.z = f2bf(acc[fr][2][reg] + bm);
        o.w = f2bf(acc[fr][3][reg] + bm);
        *(ushort4*)(vm + (size_t)m * NTOK + n0 + wc * 64 + lr * 4) = o;
      }
    }
  }
}

// ---------------- S-GEMM + exp + rowsum partials (m97 structure) ------------
// A,B = qk slices (lda/ldb = 1024). Pexp cols written K-permuted.
__global__ __launch_bounds__(256, 2) void sgemm_exp_kernel(
    const u16* __restrict__ A, const u16* __restrict__ B,
    u16* __restrict__ Pexp, float* __restrict__ rsp, long pz, int gi0base)
{
  const int z = blockIdx.z;
  A    += (size_t)z * (HW_ * 1024);
  B    += (size_t)z * (HW_ * 1024);
  Pexp += (size_t)z * pz;
  const int gi0 = gi0base + z * HW_;
  const int t = threadIdx.x;
  const int m0 = blockIdx.x * 128, n0 = blockIdx.y * 128;
  const int wv = t >> 6, l = t & 63, lr = l & 15, lq = l >> 4;
  const int wr = wv >> 1, wc = wv & 1;       // 2x2 waves of 64x64
  __shared__ u16 As[128][64];
  __shared__ u16 Bs[128][64];
  f32x4 acc[4][4] = {};
  for (int k0 = 0; k0 < 512; k0 += 64) {
    #pragma unroll
    for (int it = 0; it < 4; ++it) {
      const int ci = it * 256 + t;           // 1024 chunks of 16B
      const int row = ci >> 3;
      const int c8 = (((ci & 7) ^ (row & 7)) << 3);  // inverse-swizzled src octet
      gld_lds16(A + (size_t)(m0 + row) * 1024 + k0 + c8, &As[0][0] + ci * 8);
      gld_lds16(B + (size_t)(n0 + row) * 1024 + k0 + c8, &Bs[0][0] + ci * 8);
    }
    __syncthreads();
    #pragma unroll
    for (int kk = 0; kk < 64; kk += 32) {
      bf16x8 af[4], bf[4];
      #pragma unroll
      for (int fr = 0; fr < 4; ++fr)
        af[fr] = *(const bf16x8*)swz(&As[0][0], wr * 64 + fr * 16 + lr, kk + lq * 8, 64);
      #pragma unroll
      for (int fc = 0; fc < 4; ++fc)
        bf[fc] = *(const bf16x8*)swz(&Bs[0][0], wc * 64 + fc * 16 + lr, kk + lq * 8, 64);
      #pragma unroll
      for (int fr = 0; fr < 4; ++fr)
        #pragma unroll
        for (int fc = 0; fc < 4; ++fc)
          acc[fr][fc] = MFMA16(af[fr], bf[fc], acc[fr][fc], 0, 0, 0);
    }
    __syncthreads();
  }
  // epilogue: exp2(s*scale), rowsum partial, K-permuted packed store
  const float SCL2 = 0.06376774487989831f;   // log2(e)/sqrt(512)
  #pragma unroll
  for (int fr = 0; fr < 4; ++fr) {
    #pragma unroll
    for (int reg = 0; reg < 4; ++reg) {
      const int row = m0 + wr * 64 + fr * 16 + lq * 4 + reg;
      float p0 = exp2f(acc[fr][0][reg] * SCL2);
      float p1 = exp2f(acc[fr][1][reg] * SCL2);
      float p2 = exp2f(acc[fr][2][reg] * SCL2);
      float p3 = exp2f(acc[fr][3][reg] * SCL2);
      float rsum = p0 + p1 + p2 + p3;
      ushort4 o;
      o.x = f2bf(p0); o.y = f2bf(p1); o.z = f2bf(p2); o.w = f2bf(p3);
      *(ushort4*)(Pexp + (size_t)row * 4096 + n0 + wc * 64 + lr * 4) = o;
      rsum += __shfl_xor(rsum, 1);
      rsum += __shfl_xor(rsum, 2);
      rsum += __shfl_xor(rsum, 4);
      rsum += __shfl_xor(rsum, 8);
      if (lr == 0)
        rsp[(size_t)(blockIdx.y * 2 + wc) * NTOK + gi0 + row] = rsum;
    }
  }
}

// ---------------- PV GEMM split-K, 128x128 tile ------------------------------
// A=Pexp (K-permuted tokens), B=vm (K-permuted tokens) -> positional pairing.
// Op channel cols written K-permuted.
__global__ __launch_bounds__(256, 4) void pvgemm_splitk(
    const u16* __restrict__ A, const u16* __restrict__ B,
    u16* __restrict__ Op, long spstride, int logsplit)
{
  const int z = blockIdx.z;
  const int sp = z & ((1 << logsplit) - 1);
  const int bb = z >> logsplit;
  A  += (size_t)bb * PZ_;
  B  += (size_t)bb * HW_;
  Op += (size_t)sp * spstride + (size_t)bb * 2097152;
  const int t = threadIdx.x;
  const int m0 = blockIdx.x * 128, n0 = blockIdx.y * 128;
  const int wv = t >> 6, l = t & 63, lr = l & 15, lq = l >> 4;
  const int wr = wv >> 1, wc = wv & 1;       // 2x2 waves of 64x64
  __shared__ u16 As[128][64];
  __shared__ u16 Bs[128][64];
  f32x4 acc[4][4] = {};
  const int ksize = 4096 >> logsplit;
  const int kbeg = sp * ksize;
  for (int k0 = kbeg; k0 < kbeg + ksize; k0 += 64) {
    #pragma unroll
    for (int it = 0; it < 4; ++it) {
      const int ci = it * 256 + t;           // 1024 chunks of 16B per buffer
      const int row = ci >> 3;
      const int c8 = (((ci & 7) ^ (row & 7)) << 3);  // inverse-swizzled src octet
      gld_lds16(A + (size_t)(m0 + row) * 4096 + k0 + c8, &As[0][0] + ci * 8);
      gld_lds16(B + (size_t)(n0 + row) * NTOK + k0 + c8, &Bs[0][0] + ci * 8);
    }
    __syncthreads();
    #pragma unroll
    for (int kk = 0; kk < 64; kk += 32) {
      bf16x8 af[4], bf[4];
      #pragma unroll
      for (int fr = 0; fr < 4; ++fr)
        af[fr] = *(const bf16x8*)swz(&As[0][0], wr * 64 + fr * 16 + lr, kk + lq * 8, 64);
      #pragma unroll
      for (int fc = 0; fc < 4; ++fc)
        bf[fc] = *(const bf16x8*)swz(&Bs[0][0], wc * 64 + fc * 16 + lr, kk + lq * 8, 64);
      #pragma unroll
      for (int fr = 0; fr < 4; ++fr)
        #pragma unroll
        for (int fc = 0; fc < 4; ++fc)
          acc[fr][fc] = MFMA16(af[fr], bf[fc], acc[fr][fc], 0, 0, 0);
    }
    __syncthreads();
  }
  #pragma unroll
  for (int fr = 0; fr < 4; ++fr) {
    #pragma unroll
    for (int reg = 0; reg < 4; ++reg) {
      const int m = m0 + wr * 64 + fr * 16 + lq * 4 + reg;
      ushort4 o;
      o.x = f2bf(acc[fr][0][reg]);
      o.y = f2bf(acc[fr][1][reg]);
      o.z = f2bf(acc[fr][2][reg]);
      o.w = f2bf(acc[fr][3][reg]);
      *(ushort4*)(Op + (size_t)m * 512 + n0 + wc * 64 + lr * 4) = o;
    }
  }
}

// ---------------- combine split-K partials + rowsum-normalize (folded) ------
// Positional pass-through: ao inherits Op's K-permuted channel layout.
__global__ __launch_bounds__(256) void combine_norm(const u16* __restrict__ Op,
                                                    const float* __restrict__ rsp,
                                                    u16* __restrict__ ao,
                                                    long spstride, int nsplit, int gi0) {
  const int t = threadIdx.x;
  __shared__ float rinvs[4];
  {
    const int tokl = t >> 6, jg = t & 63;
    float s = rsp[(size_t)jg * NTOK + gi0 + blockIdx.x * 4 + tokl];
    #pragma unroll
    for (int m = 1; m < 64; m <<= 1) s += __shfl_xor(s, m);
    if (jg == 0) rinvs[tokl] = 1.0f / s;
  }
  __syncthreads();
  const size_t idx8 = ((size_t)blockIdx.x * 256 + t) * 8;
  const float ri = rinvs[t >> 6];
  float v[8] = {};
  for (int s = 0; s < nsplit; ++s) {
    const u16* p = Op + (size_t)s * spstride + idx8;
    ushort4 a0 = *(const ushort4*)p;
    ushort4 a1 = *(const ushort4*)(p + 4);
    v[0] += bf2f(a0.x); v[1] += bf2f(a0.y); v[2] += bf2f(a0.z); v[3] += bf2f(a0.w);
    v[4] += bf2f(a1.x); v[5] += bf2f(a1.y); v[6] += bf2f(a1.z); v[7] += bf2f(a1.w);
  }
  ushort4 o0, o1;
  o0.x = f2bf(v[0] * ri); o0.y = f2bf(v[1] * ri);
  o0.z = f2bf(v[2] * ri); o0.w = f2bf(v[3] * ri);
  o1.x = f2bf(v[4] * ri); o1.y = f2bf(v[5] * ri);
  o1.z = f2bf(v[6] * ri); o1.w = f2bf(v[7] * ri);
  *(ushort4*)(ao + idx8)     = o0;
  *(ushort4*)(ao + idx8 + 4) = o1;
}

extern "C" void kernel_launch(void* const* d_in, const int* in_sizes, int n_in,
                              void* d_out, int out_size, void* d_ws, size_t ws_size,
                              hipStream_t stream) {
  const float* x   = (const float*)d_in[0];
  const float* gnw = (const float*)d_in[1];
  const float* gnb = (const float*)d_in[2];
  const float* qw  = (const float*)d_in[3];
  const float* qb  = (const float*)d_in[4];
  const float* kw  = (const float*)d_in[5];
  const float* kb  = (const float*)d_in[6];
  const float* vw  = (const float*)d_in[7];
  const float* vb  = (const float*)d_in[8];
  const float* pw  = (const float*)d_in[9];
  const float* pb  = (const float*)d_in[10];

  // common prefix layout (both modes)
  char* ws = (char*)d_ws;
  u16*   wqb   = (u16*)(ws + 0);             // wq then wk rows: [1024][512] bf16
  u16*   wkb   = wqb + 262144;
  u16*   wvb   = wkb + 262144;
  u16*   wpb   = wvb + 262144;               // col dim K-permuted
  float* rsp   = (float*)(ws + 2130432);     // [64][8192] f32 (2MB)
  float* gpart = rsp;                        // gn partials alias rsp (pre-sgemm)
  u16*   hT    = (u16*)(ws + 4227584);       // [8192][512] bf16, dead after qkv
  u16*   ao    = hT;                         // reuse: [2][4096][512] bf16 (K-permuted ch)
  u16*   qk    = (u16*)(ws + 12616192);      // [8192][1024] bf16 (q|k, K-permuted)
  u16*   vm    = (u16*)(ws + 29393408);      // [512][8192] bf16 (K-permuted tokens)

  // big mode (ws >= ~138.5MB): both-batch Pexp + 4-way split-K Op partials
  const bool big = ws_size >= 138445312ULL;
  u16* OpB   = (u16*)(ws + 37782016);        // [4][2][4096][512] bf16 (33.5MB)
  u16* PexpB = (u16*)(ws + 71336448);        // [2][4096][4096] bf16 (67MB)
  // fallback (ws >= 77.66MB proven): single-batch Pexp, Op strided over qk
  u16* PexpS = (u16*)(ws + 37782016);        // [4096][4096] bf16 (33.5MB)

  head_kernel<<<1536, 256, 0, stream>>>(qw, kw, vw, pw, wqb, x, gpart);
  gn_apply_kernel<<<dim3(64, 8, 2), 256, 0, stream>>>(x, gnw, gnb, gpart, hT);
  // merged q+k (512 blocks) and v (256 blocks) in one dispatch
  qkv_kernel<<<768, 256, 0, stream>>>(hT, wqb, wvb, qb, kb, vb, qk, vm);

  if (big) {
    sgemm_exp_kernel<<<dim3(32, 32, 2), 256, 0, stream>>>(qk, qk + 512, PexpB, rsp, PZ_, 0);
    pvgemm_splitk<<<dim3(32, 4, 8), 256, 0, stream>>>(PexpB, vm, OpB, 4194304L, 2);
    combine_norm<<<2048, 256, 0, stream>>>(OpB, rsp, ao, 4194304L, 4, 0);
  } else {
    for (int b = 0; b < 2; ++b) {
      const u16* qkb = qk + (size_t)b * HW_ * 1024;
      sgemm_exp_kernel<<<dim3(32, 32, 1), 256, 0, stream>>>(qkb, qkb + 512, PexpS, rsp, 0L, b * HW_);
      pvgemm_splitk<<<dim3(32, 4, 2), 256, 0, stream>>>(PexpS, vm + (size_t)b * HW_, qk, 2097152L, 1);
      combine_norm<<<1024, 256, 0, stream>>>(qk, rsp, ao + (size_t)b * HW_ * C_, 2097152L, 2, b * HW_);
    }
  }
  // proj + bias + residual: A=wpb (cols K-permuted), B=ao (cols K-permuted)
  gemm_abt<0, 1><<<dim3(8, 64, 2), 256, 0, stream>>>(wpb, 512, ao, 512, 2097152L, pb, x, d_out, 4096, 2097152L, 512);
}

// Round 13
// 142.466 us; speedup vs baseline: 1.2329x; 1.0142x over previous
//
#include <hip/hip_runtime.h>
#include <hip/hip_bf16.h>

#define C_   512
#define HW_  4096
#define NTOK 8192
#define PZ_  16777216L   // Pexp batch stride (elems) in big mode

typedef __attribute__((ext_vector_type(8))) short bf16x8;
typedef __attribute__((ext_vector_type(4))) float f32x4;
typedef unsigned short u16;

#define MFMA16 __builtin_amdgcn_mfma_f32_16x16x32_bf16

__device__ __forceinline__ u16 f2bf(float f) {
  unsigned int u = __float_as_uint(f);
  u += 0x7fffu + ((u >> 16) & 1u);
  return (u16)(u >> 16);
}

// hardware packed f32->bf16 RNE conversion (v_cvt_pk_bf16_f32)
__device__ __forceinline__ unsigned pk2(float a, float b) {
  __hip_bfloat162 h = __float22bfloat162_rn(make_float2(a, b));
  return *reinterpret_cast<unsigned*>(&h);
}

__device__ __forceinline__ float bf2f(u16 v) {
  return __uint_as_float((unsigned)v << 16);
}

__device__ __forceinline__ void gld_lds16(const u16* g, u16* l) {
  __builtin_amdgcn_global_load_lds(
      (const __attribute__((address_space(1))) void*)g,
      (__attribute__((address_space(3))) void*)l, 16, 0, 0);
}

// swizzled LDS chunk address: logical (row, u16-col) -> physical u16 offset.
__device__ __forceinline__ const u16* swz(const u16* base, int row, int col, int ldu16) {
  return base + (size_t)row * ldu16 + ((((col >> 3) ^ (row & 7)) << 3) | (col & 7));
}

// K-PERMUTED STORAGE: within each 64-wide K group, logical col g*64+f*16+r
// stored at g*64 + r*4 + f (epilogue lane -> one ushort4 store). Consumers
// pair operands positionally; MFMA k-reductions unaffected. Applied to:
// qk cols, Pexp cols, vm token cols, Op/ao channel cols, wpb channel cols.

// ---------------- head: wcast (bid<1024) + gn_stats1 (bid>=1024) ------------
__global__ __launch_bounds__(256) void head_kernel(
    const float* __restrict__ qw, const float* __restrict__ kw,
    const float* __restrict__ vw, const float* __restrict__ pw,
    u16* __restrict__ wout, const float* __restrict__ x,
    float* __restrict__ gpart) {
  const int bid = blockIdx.x;
  const int t = threadIdx.x;
  if (bid < 1024) {
    int gid = bid * 256 + t;
    int which = gid >> 16;
    const float* src = which == 0 ? qw : which == 1 ? kw : which == 2 ? vw : pw;
    int loc = (gid & 65535) * 4;
    float4 v = *(const float4*)(src + loc);
    if (which == 3) {
      // wpb: permute channel (col) dim to match ao's stored layout
      const int row = loc >> 9, c = loc & 511;
      const int g = c & ~63, f = (c >> 4) & 3, r0 = c & 15;
      u16* base = wout + ((size_t)3 << 18) + (size_t)row * 512 + g;
      base[(r0 + 0) * 4 + f] = f2bf(v.x);
      base[(r0 + 1) * 4 + f] = f2bf(v.y);
      base[(r0 + 2) * 4 + f] = f2bf(v.z);
      base[(r0 + 3) * 4 + f] = f2bf(v.w);
    } else {
      uint2 o;
      o.x = pk2(v.x, v.y);
      o.y = pk2(v.z, v.w);
      *(uint2*)(wout + ((size_t)which << 18) + loc) = o;
    }
    return;
  }
  const int gb = bid - 1024;          // 512 blocks: group = gb>>3, chunk = gb&7
  const float4* p = (const float4*)(x + (size_t)(gb >> 3) * 65536 + (gb & 7) * 8192);
  float s = 0.0f, ss = 0.0f;
  for (int i = t; i < 2048; i += 256) {
    float4 v = p[i];
    s  += v.x + v.y + v.z + v.w;
    ss += v.x * v.x + v.y * v.y + v.z * v.z + v.w * v.w;
  }
  #pragma unroll
  for (int m = 1; m < 64; m <<= 1) { s += __shfl_xor(s, m); ss += __shfl_xor(ss, m); }
  __shared__ float rs[4], rss[4];
  const int wv = t >> 6;
  if ((t & 63) == 0) { rs[wv] = s; rss[wv] = ss; }
  __syncthreads();
  if (t == 0) {
    gpart[gb * 2]     = rs[0] + rs[1] + rs[2] + rs[3];
    gpart[gb * 2 + 1] = rss[0] + rss[1] + rss[2] + rss[3];
  }
}

// ---------------- GN apply (stage2 folded) + transpose to hT[8192][512] -----
__global__ __launch_bounds__(256) void gn_apply_kernel(const float* __restrict__ x,
                                                       const float* __restrict__ gnw,
                                                       const float* __restrict__ gnb,
                                                       const float* __restrict__ gpart,
                                                       u16* __restrict__ hT) {
  const int b = blockIdx.z, c0 = blockIdx.y * 64, hw0 = blockIdx.x * 64;
  const int t = threadIdx.x;
  __shared__ float tile[64][65];
  __shared__ float gmean[4], grstd[4];
  if (t < 4) {
    const int g = b * 32 + (c0 >> 4) + t;
    float s = 0.0f, ss = 0.0f;
    #pragma unroll
    for (int cch = 0; cch < 8; ++cch) {
      s  += gpart[(g * 8 + cch) * 2];
      ss += gpart[(g * 8 + cch) * 2 + 1];
    }
    float mean = s * (1.0f / 65536.0f);
    float var  = fmaxf(ss * (1.0f / 65536.0f) - mean * mean, 0.0f);
    gmean[t] = mean;
    grstd[t] = rsqrtf(var + 1e-6f);
  }
  __syncthreads();
  {
    const int tx = t & 63, ty = t >> 6;  // ty 0..3
    #pragma unroll
    for (int i = 0; i < 16; ++i) {
      int cl = ty * 16 + i;
      int c = c0 + cl;
      float val = x[((size_t)(b * C_ + c)) * HW_ + hw0 + tx];
      tile[cl][tx] = (val - gmean[cl >> 4]) * grstd[cl >> 4] * gnw[c] + gnb[c];
    }
  }
  __syncthreads();
  {
    const int cx = (t & 31) * 2, ty = t >> 5;  // ty 0..7
    #pragma unroll
    for (int i = 0; i < 8; ++i) {
      int hwl = ty * 8 + i;
      *(unsigned*)&hT[((size_t)(b * HW_ + hw0 + hwl)) * C_ + c0 + cx] =
          pk2(tile[cx][hwl], tile[cx + 1][hwl]);
    }
  }
}

// ---------------- merged QKV GEMM, 128x128 tiles, one dispatch --------------
// bid < 512: qk part -> qk[8192][1024] (cols K-permuted).
// bid >= 512: v part -> vm[512][8192] (token cols K-permuted).
__global__ __launch_bounds__(256, 4) void qkv_kernel(
    const u16* __restrict__ hT, const u16* __restrict__ wqkb,
    const u16* __restrict__ wvb,
    const float* __restrict__ qb, const float* __restrict__ kb,
    const float* __restrict__ vb,
    u16* __restrict__ qk, u16* __restrict__ vm)
{
  const int bid = blockIdx.x;
  const int t = threadIdx.x;
  const int wv = t >> 6, l = t & 63, lr = l & 15, lq = l >> 4;
  const int wr = wv >> 1, wc = wv & 1;       // 2x2 waves of 64x64
  const bool isqk = bid < 512;
  const int m0 = isqk ? (bid >> 3) * 128 : ((bid - 512) >> 6) * 128;
  const int n0 = isqk ? (bid & 7) * 128  : ((bid - 512) & 63) * 128;
  const u16* Arow = (isqk ? hT : wvb) + (size_t)m0 * 512;
  const u16* Brow = (isqk ? wqkb : hT) + (size_t)n0 * 512;
  __shared__ u16 As[128][64];
  __shared__ u16 Bs[128][64];
  f32x4 acc[4][4] = {};
  for (int k0 = 0; k0 < 512; k0 += 64) {
    #pragma unroll
    for (int it = 0; it < 4; ++it) {
      const int ci = it * 256 + t;           // 1024 chunks of 16B
      const int row = ci >> 3;
      const int c8 = (((ci & 7) ^ (row & 7)) << 3);  // inverse-swizzled src octet
      gld_lds16(Arow + (size_t)row * 512 + k0 + c8, &As[0][0] + ci * 8);
      gld_lds16(Brow + (size_t)row * 512 + k0 + c8, &Bs[0][0] + ci * 8);
    }
    __syncthreads();
    #pragma unroll
    for (int kk = 0; kk < 64; kk += 32) {
      bf16x8 af[4], bf[4];
      #pragma unroll
      for (int fr = 0; fr < 4; ++fr)
        af[fr] = *(const bf16x8*)swz(&As[0][0], wr * 64 + fr * 16 + lr, kk + lq * 8, 64);
      #pragma unroll
      for (int fc = 0; fc < 4; ++fc)
        bf[fc] = *(const bf16x8*)swz(&Bs[0][0], wc * 64 + fc * 16 + lr, kk + lq * 8, 64);
      #pragma unroll
      for (int fr = 0; fr < 4; ++fr)
        #pragma unroll
        for (int fc = 0; fc < 4; ++fc)
          acc[fr][fc] = MFMA16(af[fr], bf[fc], acc[fr][fc], 0, 0, 0);
    }
    __syncthreads();
  }
  if (isqk) {
    float bn[4];
    #pragma unroll
    for (int fc = 0; fc < 4; ++fc) {
      const int n = n0 + wc * 64 + fc * 16 + lr;     // logical col for bias
      bn[fc] = n < 512 ? qb[n] : kb[n - 512];
    }
    #pragma unroll
    for (int fr = 0; fr < 4; ++fr) {
      #pragma unroll
      for (int reg = 0; reg < 4; ++reg) {
        const int m = m0 + wr * 64 + fr * 16 + lq * 4 + reg;
        uint2 o;
        o.x = pk2(acc[fr][0][reg] + bn[0], acc[fr][1][reg] + bn[1]);
        o.y = pk2(acc[fr][2][reg] + bn[2], acc[fr][3][reg] + bn[3]);
        *(uint2*)(qk + (size_t)m * 1024 + n0 + wc * 64 + lr * 4) = o;
      }
    }
  } else {
    #pragma unroll
    for (int fr = 0; fr < 4; ++fr) {
      #pragma unroll
      for (int reg = 0; reg < 4; ++reg) {
        const int m = m0 + wr * 64 + fr * 16 + lq * 4 + reg;
        const float bm = vb[m];
        uint2 o;
        o.x = pk2(acc[fr][0][reg] + bm, acc[fr][1][reg] + bm);
        o.y = pk2(acc[fr][2][reg] + bm, acc[fr][3][reg] + bm);
        *(uint2*)(vm + (size_t)m * NTOK + n0 + wc * 64 + lr * 4) = o;
      }
    }
  }
}

// ---------------- S-GEMM + exp + rowsum partials (m97 structure) ------------
// A,B = qk slices (lda/ldb = 1024). Pexp cols written K-permuted.
__global__ __launch_bounds__(256, 2) void sgemm_exp_kernel(
    const u16* __restrict__ A, const u16* __restrict__ B,
    u16* __restrict__ Pexp, float* __restrict__ rsp, long pz, int gi0base)
{
  const int z = blockIdx.z;
  A    += (size_t)z * (HW_ * 1024);
  B    += (size_t)z * (HW_ * 1024);
  Pexp += (size_t)z * pz;
  const int gi0 = gi0base + z * HW_;
  const int t = threadIdx.x;
  const int m0 = blockIdx.x * 128, n0 = blockIdx.y * 128;
  const int wv = t >> 6, l = t & 63, lr = l & 15, lq = l >> 4;
  const int wr = wv >> 1, wc = wv & 1;       // 2x2 waves of 64x64
  __shared__ u16 As[128][64];
  __shared__ u16 Bs[128][64];
  f32x4 acc[4][4] = {};
  for (int k0 = 0; k0 < 512; k0 += 64) {
    #pragma unroll
    for (int it = 0; it < 4; ++it) {
      const int ci = it * 256 + t;           // 1024 chunks of 16B
      const int row = ci >> 3;
      const int c8 = (((ci & 7) ^ (row & 7)) << 3);  // inverse-swizzled src octet
      gld_lds16(A + (size_t)(m0 + row) * 1024 + k0 + c8, &As[0][0] + ci * 8);
      gld_lds16(B + (size_t)(n0 + row) * 1024 + k0 + c8, &Bs[0][0] + ci * 8);
    }
    __syncthreads();
    #pragma unroll
    for (int kk = 0; kk < 64; kk += 32) {
      bf16x8 af[4], bf[4];
      #pragma unroll
      for (int fr = 0; fr < 4; ++fr)
        af[fr] = *(const bf16x8*)swz(&As[0][0], wr * 64 + fr * 16 + lr, kk + lq * 8, 64);
      #pragma unroll
      for (int fc = 0; fc < 4; ++fc)
        bf[fc] = *(const bf16x8*)swz(&Bs[0][0], wc * 64 + fc * 16 + lr, kk + lq * 8, 64);
      #pragma unroll
      for (int fr = 0; fr < 4; ++fr)
        #pragma unroll
        for (int fc = 0; fc < 4; ++fc)
          acc[fr][fc] = MFMA16(af[fr], bf[fc], acc[fr][fc], 0, 0, 0);
    }
    __syncthreads();
  }
  // epilogue: exp2(s*scale), rowsum partial, K-permuted packed store
  const float SCL2 = 0.06376774487989831f;   // log2(e)/sqrt(512)
  #pragma unroll
  for (int fr = 0; fr < 4; ++fr) {
    #pragma unroll
    for (int reg = 0; reg < 4; ++reg) {
      const int row = m0 + wr * 64 + fr * 16 + lq * 4 + reg;
      float p0 = exp2f(acc[fr][0][reg] * SCL2);
      float p1 = exp2f(acc[fr][1][reg] * SCL2);
      float p2 = exp2f(acc[fr][2][reg] * SCL2);
      float p3 = exp2f(acc[fr][3][reg] * SCL2);
      float rsum = p0 + p1 + p2 + p3;
      uint2 o;
      o.x = pk2(p0, p1);
      o.y = pk2(p2, p3);
      *(uint2*)(Pexp + (size_t)row * 4096 + n0 + wc * 64 + lr * 4) = o;
      rsum += __shfl_xor(rsum, 1);
      rsum += __shfl_xor(rsum, 2);
      rsum += __shfl_xor(rsum, 4);
      rsum += __shfl_xor(rsum, 8);
      if (lr == 0)
        rsp[(size_t)(blockIdx.y * 2 + wc) * NTOK + gi0 + row] = rsum;
    }
  }
}

// ---------------- PV GEMM split-K, 128x128 tile ------------------------------
// A=Pexp (K-permuted tokens), B=vm (K-permuted tokens) -> positional pairing.
// Op channel cols written K-permuted.
__global__ __launch_bounds__(256, 4) void pvgemm_splitk(
    const u16* __restrict__ A, const u16* __restrict__ B,
    u16* __restrict__ Op, long spstride, int logsplit)
{
  const int z = blockIdx.z;
  const int sp = z & ((1 << logsplit) - 1);
  const int bb = z >> logsplit;
  A  += (size_t)bb * PZ_;
  B  += (size_t)bb * HW_;
  Op += (size_t)sp * spstride + (size_t)bb * 2097152;
  const int t = threadIdx.x;
  const int m0 = blockIdx.x * 128, n0 = blockIdx.y * 128;
  const int wv = t >> 6, l = t & 63, lr = l & 15, lq = l >> 4;
  const int wr = wv >> 1, wc = wv & 1;       // 2x2 waves of 64x64
  __shared__ u16 As[128][64];
  __shared__ u16 Bs[128][64];
  f32x4 acc[4][4] = {};
  const int ksize = 4096 >> logsplit;
  const int kbeg = sp * ksize;
  for (int k0 = kbeg; k0 < kbeg + ksize; k0 += 64) {
    #pragma unroll
    for (int it = 0; it < 4; ++it) {
      const int ci = it * 256 + t;           // 1024 chunks of 16B per buffer
      const int row = ci >> 3;
      const int c8 = (((ci & 7) ^ (row & 7)) << 3);  // inverse-swizzled src octet
      gld_lds16(A + (size_t)(m0 + row) * 4096 + k0 + c8, &As[0][0] + ci * 8);
      gld_lds16(B + (size_t)(n0 + row) * NTOK + k0 + c8, &Bs[0][0] + ci * 8);
    }
    __syncthreads();
    #pragma unroll
    for (int kk = 0; kk < 64; kk += 32) {
      bf16x8 af[4], bf[4];
      #pragma unroll
      for (int fr = 0; fr < 4; ++fr)
        af[fr] = *(const bf16x8*)swz(&As[0][0], wr * 64 + fr * 16 + lr, kk + lq * 8, 64);
      #pragma unroll
      for (int fc = 0; fc < 4; ++fc)
        bf[fc] = *(const bf16x8*)swz(&Bs[0][0], wc * 64 + fc * 16 + lr, kk + lq * 8, 64);
      #pragma unroll
      for (int fr = 0; fr < 4; ++fr)
        #pragma unroll
        for (int fc = 0; fc < 4; ++fc)
          acc[fr][fc] = MFMA16(af[fr], bf[fc], acc[fr][fc], 0, 0, 0);
    }
    __syncthreads();
  }
  #pragma unroll
  for (int fr = 0; fr < 4; ++fr) {
    #pragma unroll
    for (int reg = 0; reg < 4; ++reg) {
      const int m = m0 + wr * 64 + fr * 16 + lq * 4 + reg;
      uint2 o;
      o.x = pk2(acc[fr][0][reg], acc[fr][1][reg]);
      o.y = pk2(acc[fr][2][reg], acc[fr][3][reg]);
      *(uint2*)(Op + (size_t)m * 512 + n0 + wc * 64 + lr * 4) = o;
    }
  }
}

// ---------------- combine split-K partials + rowsum-normalize (folded) ------
__global__ __launch_bounds__(256) void combine_norm(const u16* __restrict__ Op,
                                                    const float* __restrict__ rsp,
                                                    u16* __restrict__ ao,
                                                    long spstride, int nsplit, int gi0) {
  const int t = threadIdx.x;
  __shared__ float rinvs[4];
  {
    const int tokl = t >> 6, jg = t & 63;
    float s = rsp[(size_t)jg * NTOK + gi0 + blockIdx.x * 4 + tokl];
    #pragma unroll
    for (int m = 1; m < 64; m <<= 1) s += __shfl_xor(s, m);
    if (jg == 0) rinvs[tokl] = 1.0f / s;
  }
  __syncthreads();
  const size_t idx8 = ((size_t)blockIdx.x * 256 + t) * 8;
  const float ri = rinvs[t >> 6];
  float v[8] = {};
  for (int s = 0; s < nsplit; ++s) {
    const u16* p = Op + (size_t)s * spstride + idx8;
    ushort4 a0 = *(const ushort4*)p;
    ushort4 a1 = *(const ushort4*)(p + 4);
    v[0] += bf2f(a0.x); v[1] += bf2f(a0.y); v[2] += bf2f(a0.z); v[3] += bf2f(a0.w);
    v[4] += bf2f(a1.x); v[5] += bf2f(a1.y); v[6] += bf2f(a1.z); v[7] += bf2f(a1.w);
  }
  uint2 o0, o1;
  o0.x = pk2(v[0] * ri, v[1] * ri);
  o0.y = pk2(v[2] * ri, v[3] * ri);
  o1.x = pk2(v[4] * ri, v[5] * ri);
  o1.y = pk2(v[6] * ri, v[7] * ri);
  *(uint2*)(ao + idx8)     = o0;
  *(uint2*)(ao + idx8 + 4) = o1;
}

// ---------------- proj GEMM, 128x128 tile + bias + fp32 residual ------------
// A=wpb [512][512] (cols K-permuted), B=ao [4096][512] (cols K-permuted),
// out D[c_out][tok] fp32 = acc + pb[m] + x[idx]. z = batch.
__global__ __launch_bounds__(256, 4) void projgemm_kernel(
    const u16* __restrict__ A, const u16* __restrict__ B,
    const float* __restrict__ bias, const float* __restrict__ resid,
    float* __restrict__ D)
{
  const int z = blockIdx.z;
  B     += (size_t)z * 2097152;
  resid += (size_t)z * 2097152;
  D     += (size_t)z * 2097152;
  const int t = threadIdx.x;
  const int m0 = blockIdx.x * 128, n0 = blockIdx.y * 128;
  const int wv = t >> 6, l = t & 63, lr = l & 15, lq = l >> 4;
  const int wr = wv >> 1, wc = wv & 1;       // 2x2 waves of 64x64
  __shared__ u16 As[128][64];
  __shared__ u16 Bs[128][64];
  f32x4 acc[4][4] = {};
  for (int k0 = 0; k0 < 512; k0 += 64) {
    #pragma unroll
    for (int it = 0; it < 4; ++it) {
      const int ci = it * 256 + t;           // 1024 chunks of 16B
      const int row = ci >> 3;
      const int c8 = (((ci & 7) ^ (row & 7)) << 3);  // inverse-swizzled src octet
      gld_lds16(A + (size_t)(m0 + row) * 512 + k0 + c8, &As[0][0] + ci * 8);
      gld_lds16(B + (size_t)(n0 + row) * 512 + k0 + c8, &Bs[0][0] + ci * 8);
    }
    __syncthreads();
    #pragma unroll
    for (int kk = 0; kk < 64; kk += 32) {
      bf16x8 af[4], bf[4];
      #pragma unroll
      for (int fr = 0; fr < 4; ++fr)
        af[fr] = *(const bf16x8*)swz(&As[0][0], wr * 64 + fr * 16 + lr, kk + lq * 8, 64);
      #pragma unroll
      for (int fc = 0; fc < 4; ++fc)
        bf[fc] = *(const bf16x8*)swz(&Bs[0][0], wc * 64 + fc * 16 + lr, kk + lq * 8, 64);
      #pragma unroll
      for (int fr = 0; fr < 4; ++fr)
        #pragma unroll
        for (int fc = 0; fc < 4; ++fc)
          acc[fr][fc] = MFMA16(af[fr], bf[fc], acc[fr][fc], 0, 0, 0);
    }
    __syncthreads();
  }
  #pragma unroll
  for (int fr = 0; fr < 4; ++fr) {
    #pragma unroll
    for (int reg = 0; reg < 4; ++reg) {
      const int m = m0 + wr * 64 + fr * 16 + lq * 4 + reg;
      const float bm = bias[m];
      #pragma unroll
      for (int fc = 0; fc < 4; ++fc) {
        const int n = n0 + wc * 64 + fc * 16 + lr;
        const size_t idx = (size_t)m * HW_ + n;
        D[idx] = acc[fr][fc][reg] + bm + resid[idx];
      }
    }
  }
}

extern "C" void kernel_launch(void* const* d_in, const int* in_sizes, int n_in,
                              void* d_out, int out_size, void* d_ws, size_t ws_size,
                              hipStream_t stream) {
  const float* x   = (const float*)d_in[0];
  const float* gnw = (const float*)d_in[1];
  const float* gnb = (const float*)d_in[2];
  const float* qw  = (const float*)d_in[3];
  const float* qb  = (const float*)d_in[4];
  const float* kw  = (const float*)d_in[5];
  const float* kb  = (const float*)d_in[6];
  const float* vw  = (const float*)d_in[7];
  const float* vb  = (const float*)d_in[8];
  const float* pw  = (const float*)d_in[9];
  const float* pb  = (const float*)d_in[10];

  // common prefix layout (both modes)
  char* ws = (char*)d_ws;
  u16*   wqb   = (u16*)(ws + 0);             // wq then wk rows: [1024][512] bf16
  u16*   wkb   = wqb + 262144;
  u16*   wvb   = wkb + 262144;
  u16*   wpb   = wvb + 262144;               // col dim K-permuted
  float* rsp   = (float*)(ws + 2130432);     // [64][8192] f32 (2MB)
  float* gpart = rsp;                        // gn partials alias rsp (pre-sgemm)
  u16*   hT    = (u16*)(ws + 4227584);       // [8192][512] bf16, dead after qkv
  u16*   ao    = hT;                         // reuse: [2][4096][512] bf16 (K-permuted ch)
  u16*   qk    = (u16*)(ws + 12616192);      // [8192][1024] bf16 (q|k, K-permuted)
  u16*   vm    = (u16*)(ws + 29393408);      // [512][8192] bf16 (K-permuted tokens)

  // big mode (ws >= ~138.5MB): both-batch Pexp + 4-way split-K Op partials
  const bool big = ws_size >= 138445312ULL;
  u16* OpB   = (u16*)(ws + 37782016);        // [4][2][4096][512] bf16 (33.5MB)
  u16* PexpB = (u16*)(ws + 71336448);        // [2][4096][4096] bf16 (67MB)
  // fallback (ws >= 77.66MB proven): single-batch Pexp, Op strided over qk
  u16* PexpS = (u16*)(ws + 37782016);        // [4096][4096] bf16 (33.5MB)

  head_kernel<<<1536, 256, 0, stream>>>(qw, kw, vw, pw, wqb, x, gpart);
  gn_apply_kernel<<<dim3(64, 8, 2), 256, 0, stream>>>(x, gnw, gnb, gpart, hT);
  // merged q+k (512 blocks) and v (256 blocks) in one dispatch
  qkv_kernel<<<768, 256, 0, stream>>>(hT, wqb, wvb, qb, kb, vb, qk, vm);

  if (big) {
    sgemm_exp_kernel<<<dim3(32, 32, 2), 256, 0, stream>>>(qk, qk + 512, PexpB, rsp, PZ_, 0);
    pvgemm_splitk<<<dim3(32, 4, 8), 256, 0, stream>>>(PexpB, vm, OpB, 4194304L, 2);
    combine_norm<<<2048, 256, 0, stream>>>(OpB, rsp, ao, 4194304L, 4, 0);
  } else {
    for (int b = 0; b < 2; ++b) {
      const u16* qkb = qk + (size_t)b * HW_ * 1024;
      sgemm_exp_kernel<<<dim3(32, 32, 1), 256, 0, stream>>>(qkb, qkb + 512, PexpS, rsp, 0L, b * HW_);
      pvgemm_splitk<<<dim3(32, 4, 2), 256, 0, stream>>>(PexpS, vm + (size_t)b * HW_, qk, 2097152L, 1);
      combine_norm<<<1024, 256, 0, stream>>>(qk, rsp, ao + (size_t)b * HW_ * C_, 2097152L, 2, b * HW_);
    }
  }
  // proj + bias + residual: A=wpb (cols K-permuted), B=ao (cols K-permuted)
  projgemm_kernel<<<dim3(4, 32, 2), 256, 0, stream>>>(wpb, ao, pb, x, (float*)d_out);
}

// Round 14
// 127.020 us; speedup vs baseline: 1.3829x; 1.1216x over previous
//
#include <hip/hip_runtime.h>
#include <hip/hip_bf16.h>

#define C_   512
#define HW_  4096
#define NTOK 8192
#define PZ_  16777216L   // Pexp batch stride (BYTES, fp8) in big mode

typedef __attribute__((ext_vector_type(8))) short bf16x8;
typedef __attribute__((ext_vector_type(4))) float f32x4;
typedef unsigned short u16;
typedef unsigned char u8;
typedef long i64;

#define MFMA16 __builtin_amdgcn_mfma_f32_16x16x32_bf16
#define MFMA8  __builtin_amdgcn_mfma_f32_16x16x32_fp8_fp8

__device__ __forceinline__ u16 f2bf(float f) {
  unsigned int u = __float_as_uint(f);
  u += 0x7fffu + ((u >> 16) & 1u);
  return (u16)(u >> 16);
}

// hardware packed f32->bf16 RNE (v_cvt_pk_bf16_f32)
__device__ __forceinline__ unsigned pk2(float a, float b) {
  __hip_bfloat162 h = __float22bfloat162_rn(make_float2(a, b));
  return *reinterpret_cast<unsigned*>(&h);
}

// hardware packed f32->fp8 e4m3 (v_cvt_pk_fp8_f32), 4 values -> u32
__device__ __forceinline__ unsigned pk4f8(float a, float b, float c, float d) {
  unsigned r = __builtin_amdgcn_cvt_pk_fp8_f32(a, b, 0u, false);
  return __builtin_amdgcn_cvt_pk_fp8_f32(c, d, r, true);
}

__device__ __forceinline__ float bf2f(u16 v) {
  return __uint_as_float((unsigned)v << 16);
}

__device__ __forceinline__ void gld_lds16(const void* g, void* l) {
  __builtin_amdgcn_global_load_lds(
      (const __attribute__((address_space(1))) void*)g,
      (__attribute__((address_space(3))) void*)l, 16, 0, 0);
}

// bf16 LDS swizzle (128-B rows, 8 chunks of 16B): chunk ^= row&7
__device__ __forceinline__ const u16* swz(const u16* base, int row, int col, int ldu16) {
  return base + (size_t)row * ldu16 + ((((col >> 3) ^ (row & 7)) << 3) | (col & 7));
}

// fp8 LDS tile [128 rows][64 B], 4 chunks of 16B/row: chunk ^= (row>>1)&3.
// frag addr for (row, kk-half h, lq): chunk = h*2+(lq>>1), within = (lq&1)*8.
__device__ __forceinline__ const i64* swz8(const u8* base, int row, int h, int lq) {
  const int chunk = (h * 2 + (lq >> 1)) ^ ((row >> 1) & 3);
  return (const i64*)(base + row * 64 + (chunk << 4) + (lq & 1) * 8);
}

// K-PERMUTED STORAGE (within each 64-wide K group, logical col g*64+f*16+r
// stored at g*64+r*4+f). Consumers pair operands positionally -> MFMA
// k-reductions unaffected. Applied to qk/Pexp/vm (fp8), Op/ao/wpb (bf16).

// ---------------- head: wcast (bid<1024) + gn_stats1 (bid>=1024) ------------
__global__ __launch_bounds__(256) void head_kernel(
    const float* __restrict__ qw, const float* __restrict__ kw,
    const float* __restrict__ vw, const float* __restrict__ pw,
    u16* __restrict__ wout, const float* __restrict__ x,
    float* __restrict__ gpart) {
  const int bid = blockIdx.x;
  const int t = threadIdx.x;
  if (bid < 1024) {
    int gid = bid * 256 + t;
    int which = gid >> 16;
    const float* src = which == 0 ? qw : which == 1 ? kw : which == 2 ? vw : pw;
    int loc = (gid & 65535) * 4;
    float4 v = *(const float4*)(src + loc);
    if (which == 3) {
      // wpb: permute channel (col) dim to match ao's stored layout
      const int row = loc >> 9, c = loc & 511;
      const int g = c & ~63, f = (c >> 4) & 3, r0 = c & 15;
      u16* base = wout + ((size_t)3 << 18) + (size_t)row * 512 + g;
      base[(r0 + 0) * 4 + f] = f2bf(v.x);
      base[(r0 + 1) * 4 + f] = f2bf(v.y);
      base[(r0 + 2) * 4 + f] = f2bf(v.z);
      base[(r0 + 3) * 4 + f] = f2bf(v.w);
    } else {
      uint2 o;
      o.x = pk2(v.x, v.y);
      o.y = pk2(v.z, v.w);
      *(uint2*)(wout + ((size_t)which << 18) + loc) = o;
    }
    return;
  }
  const int gb = bid - 1024;          // 512 blocks: group = gb>>3, chunk = gb&7
  const float4* p = (const float4*)(x + (size_t)(gb >> 3) * 65536 + (gb & 7) * 8192);
  float s = 0.0f, ss = 0.0f;
  for (int i = t; i < 2048; i += 256) {
    float4 v = p[i];
    s  += v.x + v.y + v.z + v.w;
    ss += v.x * v.x + v.y * v.y + v.z * v.z + v.w * v.w;
  }
  #pragma unroll
  for (int m = 1; m < 64; m <<= 1) { s += __shfl_xor(s, m); ss += __shfl_xor(ss, m); }
  __shared__ float rs[4], rss[4];
  const int wv = t >> 6;
  if ((t & 63) == 0) { rs[wv] = s; rss[wv] = ss; }
  __syncthreads();
  if (t == 0) {
    gpart[gb * 2]     = rs[0] + rs[1] + rs[2] + rs[3];
    gpart[gb * 2 + 1] = rss[0] + rss[1] + rss[2] + rss[3];
  }
}

// ---------------- GN apply (stage2 folded) + transpose to hT[8192][512] -----
__global__ __launch_bounds__(256) void gn_apply_kernel(const float* __restrict__ x,
                                                       const float* __restrict__ gnw,
                                                       const float* __restrict__ gnb,
                                                       const float* __restrict__ gpart,
                                                       u16* __restrict__ hT) {
  const int b = blockIdx.z, c0 = blockIdx.y * 64, hw0 = blockIdx.x * 64;
  const int t = threadIdx.x;
  __shared__ float tile[64][65];
  __shared__ float gmean[4], grstd[4];
  if (t < 4) {
    const int g = b * 32 + (c0 >> 4) + t;
    float s = 0.0f, ss = 0.0f;
    #pragma unroll
    for (int cch = 0; cch < 8; ++cch) {
      s  += gpart[(g * 8 + cch) * 2];
      ss += gpart[(g * 8 + cch) * 2 + 1];
    }
    float mean = s * (1.0f / 65536.0f);
    float var  = fmaxf(ss * (1.0f / 65536.0f) - mean * mean, 0.0f);
    gmean[t] = mean;
    grstd[t] = rsqrtf(var + 1e-6f);
  }
  __syncthreads();
  {
    const int tx = t & 63, ty = t >> 6;  // ty 0..3
    #pragma unroll
    for (int i = 0; i < 16; ++i) {
      int cl = ty * 16 + i;
      int c = c0 + cl;
      float val = x[((size_t)(b * C_ + c)) * HW_ + hw0 + tx];
      tile[cl][tx] = (val - gmean[cl >> 4]) * grstd[cl >> 4] * gnw[c] + gnb[c];
    }
  }
  __syncthreads();
  {
    const int cx = (t & 31) * 2, ty = t >> 5;  // ty 0..7
    #pragma unroll
    for (int i = 0; i < 8; ++i) {
      int hwl = ty * 8 + i;
      *(unsigned*)&hT[((size_t)(b * HW_ + hw0 + hwl)) * C_ + c0 + cx] =
          pk2(tile[cx][hwl], tile[cx + 1][hwl]);
    }
  }
}

// ---------------- merged QKV GEMM (bf16 in), fp8 K-permuted out -------------
// bid < 512: qk part -> qk[8192][1024] fp8. bid >= 512: v -> vm[512][8192] fp8.
__global__ __launch_bounds__(256, 4) void qkv_kernel(
    const u16* __restrict__ hT, const u16* __restrict__ wqkb,
    const u16* __restrict__ wvb,
    const float* __restrict__ qb, const float* __restrict__ kb,
    const float* __restrict__ vb,
    u8* __restrict__ qk, u8* __restrict__ vm)
{
  const int bid = blockIdx.x;
  const int t = threadIdx.x;
  const int wv = t >> 6, l = t & 63, lr = l & 15, lq = l >> 4;
  const int wr = wv >> 1, wc = wv & 1;       // 2x2 waves of 64x64
  const bool isqk = bid < 512;
  const int m0 = isqk ? (bid >> 3) * 128 : ((bid - 512) >> 6) * 128;
  const int n0 = isqk ? (bid & 7) * 128  : ((bid - 512) & 63) * 128;
  const u16* Arow = (isqk ? hT : wvb) + (size_t)m0 * 512;
  const u16* Brow = (isqk ? wqkb : hT) + (size_t)n0 * 512;
  __shared__ u16 As[128][64];
  __shared__ u16 Bs[128][64];
  f32x4 acc[4][4] = {};
  for (int k0 = 0; k0 < 512; k0 += 64) {
    #pragma unroll
    for (int it = 0; it < 4; ++it) {
      const int ci = it * 256 + t;           // 1024 chunks of 16B
      const int row = ci >> 3;
      const int c8 = (((ci & 7) ^ (row & 7)) << 3);  // inverse-swizzled src octet
      gld_lds16(Arow + (size_t)row * 512 + k0 + c8, &As[0][0] + ci * 8);
      gld_lds16(Brow + (size_t)row * 512 + k0 + c8, &Bs[0][0] + ci * 8);
    }
    __syncthreads();
    #pragma unroll
    for (int kk = 0; kk < 64; kk += 32) {
      bf16x8 af[4], bf[4];
      #pragma unroll
      for (int fr = 0; fr < 4; ++fr)
        af[fr] = *(const bf16x8*)swz(&As[0][0], wr * 64 + fr * 16 + lr, kk + lq * 8, 64);
      #pragma unroll
      for (int fc = 0; fc < 4; ++fc)
        bf[fc] = *(const bf16x8*)swz(&Bs[0][0], wc * 64 + fc * 16 + lr, kk + lq * 8, 64);
      #pragma unroll
      for (int fr = 0; fr < 4; ++fr)
        #pragma unroll
        for (int fc = 0; fc < 4; ++fc)
          acc[fr][fc] = MFMA16(af[fr], bf[fc], acc[fr][fc], 0, 0, 0);
    }
    __syncthreads();
  }
  if (isqk) {
    float bn[4];
    #pragma unroll
    for (int fc = 0; fc < 4; ++fc) {
      const int n = n0 + wc * 64 + fc * 16 + lr;     // logical col for bias
      bn[fc] = n < 512 ? qb[n] : kb[n - 512];
    }
    #pragma unroll
    for (int fr = 0; fr < 4; ++fr) {
      #pragma unroll
      for (int reg = 0; reg < 4; ++reg) {
        const int m = m0 + wr * 64 + fr * 16 + lq * 4 + reg;
        *(unsigned*)(qk + (size_t)m * 1024 + n0 + wc * 64 + lr * 4) =
            pk4f8(acc[fr][0][reg] + bn[0], acc[fr][1][reg] + bn[1],
                  acc[fr][2][reg] + bn[2], acc[fr][3][reg] + bn[3]);
      }
    }
  } else {
    #pragma unroll
    for (int fr = 0; fr < 4; ++fr) {
      #pragma unroll
      for (int reg = 0; reg < 4; ++reg) {
        const int m = m0 + wr * 64 + fr * 16 + lq * 4 + reg;
        const float bm = vb[m];
        *(unsigned*)(vm + (size_t)m * NTOK + n0 + wc * 64 + lr * 4) =
            pk4f8(acc[fr][0][reg] + bm, acc[fr][1][reg] + bm,
                  acc[fr][2][reg] + bm, acc[fr][3][reg] + bm);
      }
    }
  }
}

// ---------------- S-GEMM fp8 + exp + rowsum partials -------------------------
// A,B = qk fp8 slices (row stride 1024 B). Pexp fp8, K-permuted cols.
// P' = exp2(s*SCL2 - 1): max ~2^7 << 448 (e4m3 range), typical in normal range.
__global__ __launch_bounds__(256, 4) void sgemm_exp_kernel(
    const u8* __restrict__ A, const u8* __restrict__ B,
    u8* __restrict__ Pexp, float* __restrict__ rsp, long pz, int gi0base)
{
  const int z = blockIdx.z;
  A    += (size_t)z * (HW_ * 1024);
  B    += (size_t)z * (HW_ * 1024);
  Pexp += (size_t)z * pz;
  const int gi0 = gi0base + z * HW_;
  const int t = threadIdx.x;
  const int m0 = blockIdx.x * 128, n0 = blockIdx.y * 128;
  const int wv = t >> 6, l = t & 63, lr = l & 15, lq = l >> 4;
  const int wr = wv >> 1, wc = wv & 1;       // 2x2 waves of 64x64
  __shared__ u8 As[8192];                    // [128][64] fp8, swizzled
  __shared__ u8 Bs[8192];
  f32x4 acc[4][4] = {};
  for (int k0 = 0; k0 < 512; k0 += 64) {
    #pragma unroll
    for (int it = 0; it < 2; ++it) {
      const int ci = it * 256 + t;           // 512 chunks of 16B per tile
      const int row = ci >> 2;
      const int src = (((ci & 3) ^ ((row >> 1) & 3)) << 4);
      gld_lds16(A + (size_t)(m0 + row) * 1024 + k0 + src, As + ci * 16);
      gld_lds16(B + (size_t)(n0 + row) * 1024 + k0 + src, Bs + ci * 16);
    }
    __syncthreads();
    #pragma unroll
    for (int h = 0; h < 2; ++h) {
      i64 af[4], bf[4];
      #pragma unroll
      for (int fr = 0; fr < 4; ++fr)
        af[fr] = *swz8(As, wr * 64 + fr * 16 + lr, h, lq);
      #pragma unroll
      for (int fc = 0; fc < 4; ++fc)
        bf[fc] = *swz8(Bs, wc * 64 + fc * 16 + lr, h, lq);
      #pragma unroll
      for (int fr = 0; fr < 4; ++fr)
        #pragma unroll
        for (int fc = 0; fc < 4; ++fc)
          acc[fr][fc] = MFMA8(af[fr], bf[fc], acc[fr][fc], 0, 0, 0);
    }
    __syncthreads();
  }
  const float SCL2 = 0.06376774487989831f;   // log2(e)/sqrt(512)
  #pragma unroll
  for (int fr = 0; fr < 4; ++fr) {
    #pragma unroll
    for (int reg = 0; reg < 4; ++reg) {
      const int row = m0 + wr * 64 + fr * 16 + lq * 4 + reg;
      float p0 = exp2f(acc[fr][0][reg] * SCL2 - 1.0f);
      float p1 = exp2f(acc[fr][1][reg] * SCL2 - 1.0f);
      float p2 = exp2f(acc[fr][2][reg] * SCL2 - 1.0f);
      float p3 = exp2f(acc[fr][3][reg] * SCL2 - 1.0f);
      float rsum = p0 + p1 + p2 + p3;
      *(unsigned*)(Pexp + (size_t)row * 4096 + n0 + wc * 64 + lr * 4) =
          pk4f8(p0, p1, p2, p3);
      rsum += __shfl_xor(rsum, 1);
      rsum += __shfl_xor(rsum, 2);
      rsum += __shfl_xor(rsum, 4);
      rsum += __shfl_xor(rsum, 8);
      if (lr == 0)
        rsp[(size_t)(blockIdx.y * 2 + wc) * NTOK + gi0 + row] = rsum;
    }
  }
}

// ---------------- PV GEMM fp8 split-K, 128x128 tile --------------------------
// A=Pexp fp8 (row 4096 B), B=vm fp8 (row 8192 B). Op bf16, K-permuted ch.
__global__ __launch_bounds__(256, 4) void pvgemm_splitk(
    const u8* __restrict__ A, const u8* __restrict__ B,
    u16* __restrict__ Op, long spstride, int logsplit)
{
  const int z = blockIdx.z;
  const int sp = z & ((1 << logsplit) - 1);
  const int bb = z >> logsplit;
  A  += (size_t)bb * PZ_;
  B  += (size_t)bb * HW_;
  Op += (size_t)sp * spstride + (size_t)bb * 2097152;
  const int t = threadIdx.x;
  const int m0 = blockIdx.x * 128, n0 = blockIdx.y * 128;
  const int wv = t >> 6, l = t & 63, lr = l & 15, lq = l >> 4;
  const int wr = wv >> 1, wc = wv & 1;       // 2x2 waves of 64x64
  __shared__ u8 As[8192];
  __shared__ u8 Bs[8192];
  f32x4 acc[4][4] = {};
  const int ksize = 4096 >> logsplit;
  const int kbeg = sp * ksize;
  for (int k0 = kbeg; k0 < kbeg + ksize; k0 += 64) {
    #pragma unroll
    for (int it = 0; it < 2; ++it) {
      const int ci = it * 256 + t;           // 512 chunks per tile
      const int row = ci >> 2;
      const int src = (((ci & 3) ^ ((row >> 1) & 3)) << 4);
      gld_lds16(A + (size_t)(m0 + row) * 4096 + k0 + src, As + ci * 16);
      gld_lds16(B + (size_t)(n0 + row) * NTOK + k0 + src, Bs + ci * 16);
    }
    __syncthreads();
    #pragma unroll
    for (int h = 0; h < 2; ++h) {
      i64 af[4], bf[4];
      #pragma unroll
      for (int fr = 0; fr < 4; ++fr)
        af[fr] = *swz8(As, wr * 64 + fr * 16 + lr, h, lq);
      #pragma unroll
      for (int fc = 0; fc < 4; ++fc)
        bf[fc] = *swz8(Bs, wc * 64 + fc * 16 + lr, h, lq);
      #pragma unroll
      for (int fr = 0; fr < 4; ++fr)
        #pragma unroll
        for (int fc = 0; fc < 4; ++fc)
          acc[fr][fc] = MFMA8(af[fr], bf[fc], acc[fr][fc], 0, 0, 0);
    }
    __syncthreads();
  }
  #pragma unroll
  for (int fr = 0; fr < 4; ++fr) {
    #pragma unroll
    for (int reg = 0; reg < 4; ++reg) {
      const int m = m0 + wr * 64 + fr * 16 + lq * 4 + reg;
      uint2 o;
      o.x = pk2(acc[fr][0][reg], acc[fr][1][reg]);
      o.y = pk2(acc[fr][2][reg], acc[fr][3][reg]);
      *(uint2*)(Op + (size_t)m * 512 + n0 + wc * 64 + lr * 4) = o;
    }
  }
}

// ---------------- combine split-K partials + rowsum-normalize (folded) ------
__global__ __launch_bounds__(256) void combine_norm(const u16* __restrict__ Op,
                                                    const float* __restrict__ rsp,
                                                    u16* __restrict__ ao,
                                                    long spstride, int nsplit, int gi0) {
  const int t = threadIdx.x;
  __shared__ float rinvs[4];
  {
    const int tokl = t >> 6, jg = t & 63;
    float s = rsp[(size_t)jg * NTOK + gi0 + blockIdx.x * 4 + tokl];
    #pragma unroll
    for (int m = 1; m < 64; m <<= 1) s += __shfl_xor(s, m);
    if (jg == 0) rinvs[tokl] = 1.0f / s;
  }
  __syncthreads();
  const size_t idx8 = ((size_t)blockIdx.x * 256 + t) * 8;
  const float ri = rinvs[t >> 6];
  float v[8] = {};
  for (int s = 0; s < nsplit; ++s) {
    const u16* p = Op + (size_t)s * spstride + idx8;
    ushort4 a0 = *(const ushort4*)p;
    ushort4 a1 = *(const ushort4*)(p + 4);
    v[0] += bf2f(a0.x); v[1] += bf2f(a0.y); v[2] += bf2f(a0.z); v[3] += bf2f(a0.w);
    v[4] += bf2f(a1.x); v[5] += bf2f(a1.y); v[6] += bf2f(a1.z); v[7] += bf2f(a1.w);
  }
  uint2 o0, o1;
  o0.x = pk2(v[0] * ri, v[1] * ri);
  o0.y = pk2(v[2] * ri, v[3] * ri);
  o1.x = pk2(v[4] * ri, v[5] * ri);
  o1.y = pk2(v[6] * ri, v[7] * ri);
  *(uint2*)(ao + idx8)     = o0;
  *(uint2*)(ao + idx8 + 4) = o1;
}

// ---------------- proj GEMM (bf16), 128x128 tile + bias + fp32 residual -----
__global__ __launch_bounds__(256, 4) void projgemm_kernel(
    const u16* __restrict__ A, const u16* __restrict__ B,
    const float* __restrict__ bias, const float* __restrict__ resid,
    float* __restrict__ D)
{
  const int z = blockIdx.z;
  B     += (size_t)z * 2097152;
  resid += (size_t)z * 2097152;
  D     += (size_t)z * 2097152;
  const int t = threadIdx.x;
  const int m0 = blockIdx.x * 128, n0 = blockIdx.y * 128;
  const int wv = t >> 6, l = t & 63, lr = l & 15, lq = l >> 4;
  const int wr = wv >> 1, wc = wv & 1;       // 2x2 waves of 64x64
  __shared__ u16 As[128][64];
  __shared__ u16 Bs[128][64];
  f32x4 acc[4][4] = {};
  for (int k0 = 0; k0 < 512; k0 += 64) {
    #pragma unroll
    for (int it = 0; it < 4; ++it) {
      const int ci = it * 256 + t;           // 1024 chunks of 16B
      const int row = ci >> 3;
      const int c8 = (((ci & 7) ^ (row & 7)) << 3);  // inverse-swizzled src octet
      gld_lds16(A + (size_t)(m0 + row) * 512 + k0 + c8, &As[0][0] + ci * 8);
      gld_lds16(B + (size_t)(n0 + row) * 512 + k0 + c8, &Bs[0][0] + ci * 8);
    }
    __syncthreads();
    #pragma unroll
    for (int kk = 0; kk < 64; kk += 32) {
      bf16x8 af[4], bf[4];
      #pragma unroll
      for (int fr = 0; fr < 4; ++fr)
        af[fr] = *(const bf16x8*)swz(&As[0][0], wr * 64 + fr * 16 + lr, kk + lq * 8, 64);
      #pragma unroll
      for (int fc = 0; fc < 4; ++fc)
        bf[fc] = *(const bf16x8*)swz(&Bs[0][0], wc * 64 + fc * 16 + lr, kk + lq * 8, 64);
      #pragma unroll
      for (int fr = 0; fr < 4; ++fr)
        #pragma unroll
        for (int fc = 0; fc < 4; ++fc)
          acc[fr][fc] = MFMA16(af[fr], bf[fc], acc[fr][fc], 0, 0, 0);
    }
    __syncthreads();
  }
  #pragma unroll
  for (int fr = 0; fr < 4; ++fr) {
    #pragma unroll
    for (int reg = 0; reg < 4; ++reg) {
      const int m = m0 + wr * 64 + fr * 16 + lq * 4 + reg;
      const float bm = bias[m];
      #pragma unroll
      for (int fc = 0; fc < 4; ++fc) {
        const int n = n0 + wc * 64 + fc * 16 + lr;
        const size_t idx = (size_t)m * HW_ + n;
        D[idx] = acc[fr][fc][reg] + bm + resid[idx];
      }
    }
  }
}

extern "C" void kernel_launch(void* const* d_in, const int* in_sizes, int n_in,
                              void* d_out, int out_size, void* d_ws, size_t ws_size,
                              hipStream_t stream) {
  const float* x   = (const float*)d_in[0];
  const float* gnw = (const float*)d_in[1];
  const float* gnb = (const float*)d_in[2];
  const float* qw  = (const float*)d_in[3];
  const float* qb  = (const float*)d_in[4];
  const float* kw  = (const float*)d_in[5];
  const float* kb  = (const float*)d_in[6];
  const float* vw  = (const float*)d_in[7];
  const float* vb  = (const float*)d_in[8];
  const float* pw  = (const float*)d_in[9];
  const float* pb  = (const float*)d_in[10];

  // common prefix layout (both modes)
  char* ws = (char*)d_ws;
  u16*   wqb   = (u16*)(ws + 0);             // wq then wk rows: [1024][512] bf16
  u16*   wkb   = wqb + 262144;
  u16*   wvb   = wkb + 262144;
  u16*   wpb   = wvb + 262144;               // col dim K-permuted
  float* rsp   = (float*)(ws + 2130432);     // [64][8192] f32 (2MB)
  float* gpart = rsp;                        // gn partials alias rsp (pre-sgemm)
  u16*   hT    = (u16*)(ws + 4227584);       // [8192][512] bf16, dead after qkv
  u16*   ao    = hT;                         // reuse: [2][4096][512] bf16 (K-perm ch)
  u8*    qk    = (u8*)(ws + 12616192);       // [8192][1024] fp8 (q|k, K-permuted)
  u8*    vm    = (u8*)(ws + 29393408);       // [512][8192] fp8 (K-permuted tokens)

  // big mode: both-batch fp8 Pexp + 4-way split-K bf16 Op partials
  const bool big = ws_size >= 138445312ULL;
  u16* OpB   = (u16*)(ws + 37782016);        // [4][2][4096][512] bf16 (33.5MB)
  u8*  PexpB = (u8*)(ws + 71336448);         // [2][4096][4096] fp8 (33.5MB)
  // fallback (ws >= 77.66MB proven): single-batch fp8 Pexp + Op after it
  u8*  PexpS = (u8*)(ws + 37782016);         // [4096][4096] fp8 (16.8MB)
  u16* OpS   = (u16*)(ws + 54559232);        // [2][4096][512] bf16 (8MB)

  head_kernel<<<1536, 256, 0, stream>>>(qw, kw, vw, pw, wqb, x, gpart);
  gn_apply_kernel<<<dim3(64, 8, 2), 256, 0, stream>>>(x, gnw, gnb, gpart, hT);
  // merged q+k (512 blocks) and v (256 blocks) in one dispatch
  qkv_kernel<<<768, 256, 0, stream>>>(hT, wqb, wvb, qb, kb, vb, qk, vm);

  if (big) {
    sgemm_exp_kernel<<<dim3(32, 32, 2), 256, 0, stream>>>(qk, qk + 512, PexpB, rsp, PZ_, 0);
    pvgemm_splitk<<<dim3(32, 4, 8), 256, 0, stream>>>(PexpB, vm, OpB, 4194304L, 2);
    combine_norm<<<2048, 256, 0, stream>>>(OpB, rsp, ao, 4194304L, 4, 0);
  } else {
    for (int b = 0; b < 2; ++b) {
      const u8* qkb = qk + (size_t)b * HW_ * 1024;
      sgemm_exp_kernel<<<dim3(32, 32, 1), 256, 0, stream>>>(qkb, qkb + 512, PexpS, rsp, 0L, b * HW_);
      pvgemm_splitk<<<dim3(32, 4, 2), 256, 0, stream>>>(PexpS, vm + (size_t)b * HW_, OpS, 2097152L, 1);
      combine_norm<<<1024, 256, 0, stream>>>(OpS, rsp, ao + (size_t)b * HW_ * C_, 2097152L, 2, b * HW_);
    }
  }
  // proj + bias + residual: A=wpb (cols K-permuted), B=ao (cols K-permuted)
  projgemm_kernel<<<dim3(4, 32, 2), 256, 0, stream>>>(wpb, ao, pb, x, (float*)d_out);
}